// Round 3
// baseline (162003.369 us; speedup 1.0000x reference)
//
#include <hip/hip_runtime.h>
#include <hip/hip_bf16.h>

// IEBins forward. All tensors fp32; ALL internal math fp64 so depth_r matches
// the np reference far below the knife-edge scale of the hard label compare
// (cs = cd[label], bin width 5.0 at iter 0 — round 2 failed with exactly one
// bin-width 5.0 absmax from an fp32 accumulation-order flip).
// Activation storage is double when ws_size permits (212 MB), else float
// (still double accumulation).
//
// Shapes: B=2, H=120, W=160, HD=128, CD=192, BN=16, OC=256, GC=576, 6 iters.

#define HD  128
#define CDC 192
#define BN  16
#define OCH 256
#define GC  576
#define NB  2
#define HH  120
#define WW  160
#define HW  (HH*WW)
#define BHW (NB*HW)

// ---------------------------------------------------------------- init ----
template<typename ST>
__global__ __launch_bounds__(256) void k_init(const float* __restrict__ gh,
        ST* __restrict__ h, ST* __restrict__ edges, ST* __restrict__ cd){
  const int i = blockIdx.x*256 + threadIdx.x;
  const int nh = NB*HD*HW;
  if (i < nh) h[i] = (ST)gh[i];
  if (i < BHW){
    const int b = i / HW, r = i - b*HW;
    double e = 0.0;
    #pragma unroll
    for (int k=0;k<BN;++k){
      edges[(b*(BN+1)+k)*HW + r] = (ST)e;
      cd[(b*BN+k)*HW + r] = (ST)(e + 2.5);
      e += 5.0;
    }
    edges[(b*(BN+1)+BN)*HW + r] = (ST)e;   // 80
  }
}

// ------------------------------------------------------- generic conv ----
// One thread: one pixel x 4 output channels. Weight indices block/loop
// uniform (scalar loads). fp64 accumulation.
template<typename ST,int CIN,int KH,int KW,int ACT>   // ACT: 1=relu
__global__ __launch_bounds__(256) void k_conv(const ST* __restrict__ in,
        const float* __restrict__ w, const float* __restrict__ bias,
        ST* __restrict__ out, const int Cout){
  const int px = blockIdx.x*256 + threadIdx.x;
  const int o0 = blockIdx.y*4;
  const int b = px / HW, r = px - b*HW;
  const int y = r / WW, x = r - y*WW;
  double a0=(double)bias[o0+0], a1=(double)bias[o0+1],
         a2=(double)bias[o0+2], a3=(double)bias[o0+3];
  const ST* inb = in + (size_t)b*CIN*HW;
  const int PH = KH/2, PW = KW/2, WS = CIN*KH*KW;
  #pragma unroll
  for (int dy=0; dy<KH; ++dy){
    const int iy = y + dy - PH;
    if (iy < 0 || iy >= HH) continue;
    #pragma unroll
    for (int dx=0; dx<KW; ++dx){
      const int ix = x + dx - PW;
      if (ix < 0 || ix >= WW) continue;
      const ST* ip = inb + iy*WW + ix;
      const float* wp = w + (size_t)o0*WS + dy*KW + dx;
      for (int c=0; c<CIN; ++c){
        const double v = (double)ip[(size_t)c*HW];
        const int wi = c*KH*KW;
        a0 = fma(v, (double)wp[wi        ], a0);
        a1 = fma(v, (double)wp[wi +   WS ], a1);
        a2 = fma(v, (double)wp[wi + 2*WS ], a2);
        a3 = fma(v, (double)wp[wi + 3*WS ], a3);
      }
    }
  }
  double acc[4] = {a0,a1,a2,a3};
  #pragma unroll
  for (int j=0;j<4;++j){
    double v = acc[j];
    if (ACT==1) v = v > 0.0 ? v : 0.0;
    out[((size_t)b*Cout + o0 + j)*HW + r] = (ST)v;
  }
}

// -------------------------------------------------- GRU conv helpers ----
template<int C, typename PT>
__device__ __forceinline__ void acc2(const PT* __restrict__ p,
    const float* __restrict__ wa, const float* __restrict__ wb,
    double aa[4], double ab[4]){
  for (int c=0;c<C;++c){
    const double v = (double)p[(size_t)c*HW];
    const int wi = c*5;
    #pragma unroll
    for (int j=0;j<4;++j){
      aa[j] = fma(v, (double)wa[wi + j*(GC*5)], aa[j]);
      ab[j] = fma(v, (double)wb[wi + j*(GC*5)], ab[j]);
    }
  }
}
template<int C, typename PT>
__device__ __forceinline__ void acc1(const PT* __restrict__ p,
    const float* __restrict__ wa, double aa[4]){
  for (int c=0;c<C;++c){
    const double v = (double)p[(size_t)c*HW];
    const int wi = c*5;
    #pragma unroll
    for (int j=0;j<4;++j) aa[j] = fma(v, (double)wa[wi + j*(GC*5)], aa[j]);
  }
}

// Fused z,r convs (share input loads) + rgh = sigmoid(r)*h.
template<typename ST,int VERT>
__global__ __launch_bounds__(256) void k_gru_zr(
    const ST* __restrict__ h, const ST* __restrict__ d4, const float* __restrict__ ctx,
    const float* __restrict__ wz, const float* __restrict__ bz,
    const float* __restrict__ wr, const float* __restrict__ br,
    ST* __restrict__ zg, ST* __restrict__ rgh){
  const int px = blockIdx.x*256 + threadIdx.x;
  const int o0 = blockIdx.y*4;
  const int b = px / HW, r = px - b*HW;
  const int y = r / WW, x = r - y*WW;
  double az[4], ar[4];
  #pragma unroll
  for (int j=0;j<4;++j){ az[j]=(double)bz[o0+j]; ar[j]=(double)br[o0+j]; }
  const ST*    hb = h  + (size_t)b*HD *HW;
  const ST*    db = d4 + (size_t)b*OCH*HW;
  const float* cb = ctx+ (size_t)b*CDC*HW;
  #pragma unroll
  for (int k=0;k<5;++k){
    const int iy = VERT ? (y+k-2) : y;
    const int ix = VERT ? x : (x+k-2);
    if (iy<0||iy>=HH||ix<0||ix>=WW) continue;
    const int po = iy*WW + ix;
    const float* wzk = wz + (size_t)o0*GC*5 + k;
    const float* wrk = wr + (size_t)o0*GC*5 + k;
    acc2<HD >(hb+po, wzk,              wrk,              az, ar);
    acc2<OCH>(db+po, wzk + HD*5,       wrk + HD*5,       az, ar);
    acc2<CDC>(cb+po, wzk + (HD+OCH)*5, wrk + (HD+OCH)*5, az, ar);
  }
  #pragma unroll
  for (int j=0;j<4;++j){
    const int oi = (b*HD + o0 + j)*HW + r;
    zg[oi]  = (ST)(1.0/(1.0+exp(-az[j])));
    rgh[oi] = (ST)((1.0/(1.0+exp(-ar[j]))) * (double)h[oi]);
  }
}

// q conv + in-place hidden update: h = (1-z)*h + z*tanh(q).
template<typename ST,int VERT>
__global__ __launch_bounds__(256) void k_gru_q(
    const ST* __restrict__ rgh, const ST* __restrict__ d4, const float* __restrict__ ctx,
    const float* __restrict__ wq, const float* __restrict__ bq,
    const ST* __restrict__ zg, ST* __restrict__ h){
  const int px = blockIdx.x*256 + threadIdx.x;
  const int o0 = blockIdx.y*4;
  const int b = px / HW, r = px - b*HW;
  const int y = r / WW, x = r - y*WW;
  double aq[4];
  #pragma unroll
  for (int j=0;j<4;++j) aq[j]=(double)bq[o0+j];
  const ST*    gb = rgh + (size_t)b*HD *HW;
  const ST*    db = d4  + (size_t)b*OCH*HW;
  const float* cb = ctx + (size_t)b*CDC*HW;
  #pragma unroll
  for (int k=0;k<5;++k){
    const int iy = VERT ? (y+k-2) : y;
    const int ix = VERT ? x : (x+k-2);
    if (iy<0||iy>=HH||ix<0||ix>=WW) continue;
    const int po = iy*WW + ix;
    const float* wqk = wq + (size_t)o0*GC*5 + k;
    acc1<HD >(gb+po, wqk,              aq);
    acc1<OCH>(db+po, wqk + HD*5,       aq);
    acc1<CDC>(cb+po, wqk + (HD+OCH)*5, aq);
  }
  #pragma unroll
  for (int j=0;j<4;++j){
    const int oi = (b*HD + o0 + j)*HW + r;
    const double q = tanh(aq[j]);
    const double z = (double)zg[oi];
    h[oi] = (ST)((1.0-z)*(double)h[oi] + z*q);
  }
}

// ------------------- softmax + depth_r + unc + label + cs + bin update ----
template<typename ST>
__global__ __launch_bounds__(256) void k_stats(const ST* __restrict__ lg,
    ST* __restrict__ edges, ST* __restrict__ cd, float* __restrict__ out,
    const int it){
  const int px = blockIdx.x*256 + threadIdx.x;
  const int b = px / HW, r = px - b*HW;
  double l[BN], p[BN], c[BN];
  double m = -1e300;
  #pragma unroll
  for (int k=0;k<BN;++k){ l[k] = (double)lg[(b*BN+k)*HW + r]; m = l[k]>m?l[k]:m; }
  double s = 0.0;
  #pragma unroll
  for (int k=0;k<BN;++k){ p[k] = exp(l[k]-m); s += p[k]; }
  double dr = 0.0;
  #pragma unroll
  for (int k=0;k<BN;++k){ c[k] = (double)cd[(b*BN+k)*HW + r]; p[k] = p[k]/s; dr += p[k]*c[k]; }
  double var = 0.0;
  #pragma unroll
  for (int k=0;k<BN;++k){ const double d = c[k]-dr; var += p[k]*(d*d); }
  const double un = sqrt(var);
  // label from OLD edges
  int cnt = 0;
  #pragma unroll
  for (int k=1;k<BN;++k) cnt += (dr >= (double)edges[(b*(BN+1)+k)*HW + r]) ? 1 : 0;
  const double etop = (double)edges[(b*(BN+1)+BN)*HW + r];
  const int label = (dr >= etop) ? 0 : cnt;
  double csv = c[0];
  #pragma unroll
  for (int k=1;k<BN;++k) csv = (label==k) ? c[k] : csv;
  out[((0*6+it)*NB + b)*HW + r] = (float)dr;
  out[((1*6+it)*NB + b)*HW + r] = (float)csv;
  out[((2*6+it)*NB + b)*HW + r] = (float)un;
  // update bins: sequential cumsum (matching jnp) then clip
  const double start = dr - 0.5*un > 0.0 ? dr - 0.5*un : 0.0;
  const double step = un * (1.0/BN);
  double e = start;
  double prev = e < 0.0 ? 0.0 : (e > 80.0 ? 80.0 : e);
  edges[(b*(BN+1)+0)*HW + r] = (ST)prev;
  #pragma unroll
  for (int k=1;k<=BN;++k){
    e = e + step;
    const double ec = e < 0.0 ? 0.0 : (e > 80.0 ? 80.0 : e);
    edges[(b*(BN+1)+k)*HW + r] = (ST)ec;
    cd[(b*BN + (k-1))*HW + r] = (ST)(0.5*(prev + ec));
    prev = ec;
  }
}

// ----------------------------------------------------------- pipeline ----
template<typename ST>
static void run_pipeline(void* const* d_in, float* out, ST* ws, hipStream_t stream){
  const float* ctx = (const float*)d_in[1];
  const float* gh  = (const float*)d_in[2];
  const float *e1w=(const float*)d_in[3],  *e1b=(const float*)d_in[4];
  const float *e2w=(const float*)d_in[5],  *e2b=(const float*)d_in[6];
  const float *e3w=(const float*)d_in[7],  *e3b=(const float*)d_in[8];
  const float *e4w=(const float*)d_in[9],  *e4b=(const float*)d_in[10];
  const float *z1w=(const float*)d_in[11], *z1b=(const float*)d_in[12];
  const float *r1w=(const float*)d_in[13], *r1b=(const float*)d_in[14];
  const float *q1w=(const float*)d_in[15], *q1b=(const float*)d_in[16];
  const float *z2w=(const float*)d_in[17], *z2b=(const float*)d_in[18];
  const float *r2w=(const float*)d_in[19], *r2b=(const float*)d_in[20];
  const float *q2w=(const float*)d_in[21], *q2b=(const float*)d_in[22];
  const float *p1w=(const float*)d_in[23], *p1b=(const float*)d_in[24];
  const float *p2w=(const float*)d_in[25], *p2b=(const float*)d_in[26];

  ST* h    = ws;                               // NB*HD*HW
  ST* d4   = h    + (size_t)NB*HD*HW;          // NB*OCH*HW
  ST* bufA = d4   + (size_t)NB*OCH*HW;         // NB*HD*HW
  ST* bufB = bufA + (size_t)NB*HD*HW;          // NB*HD*HW
  ST* edges= bufB + (size_t)NB*HD*HW;          // NB*17*HW
  ST* cd   = edges+ (size_t)NB*(BN+1)*HW;      // NB*16*HW
  ST* lgts = cd   + (size_t)NB*BN*HW;          // NB*16*HW

  const dim3 blk(256);
  const int PXB = BHW/256;                     // 150, exact

  k_init<ST><<<dim3((NB*HD*HW+255)/256), blk, 0, stream>>>(gh, h, edges, cd);

  for (int it=0; it<6; ++it){
    k_conv<ST,16,7,7,1> <<<dim3(PXB,32), blk, 0, stream>>>(cd,   e1w, e1b, bufA, HD);
    k_conv<ST,128,3,3,1><<<dim3(PXB,32), blk, 0, stream>>>(bufA, e2w, e2b, bufB, HD);
    k_conv<ST,128,3,3,1><<<dim3(PXB,32), blk, 0, stream>>>(bufB, e3w, e3b, bufA, HD);
    k_conv<ST,128,3,3,1><<<dim3(PXB,64), blk, 0, stream>>>(bufA, e4w, e4b, d4,  OCH);
    // horizontal GRU (1x5)
    k_gru_zr<ST,0><<<dim3(PXB,32), blk, 0, stream>>>(h, d4, ctx, z1w, z1b, r1w, r1b, bufA, bufB);
    k_gru_q <ST,0><<<dim3(PXB,32), blk, 0, stream>>>(bufB, d4, ctx, q1w, q1b, bufA, h);
    // vertical GRU (5x1)
    k_gru_zr<ST,1><<<dim3(PXB,32), blk, 0, stream>>>(h, d4, ctx, z2w, z2b, r2w, r2b, bufA, bufB);
    k_gru_q <ST,1><<<dim3(PXB,32), blk, 0, stream>>>(bufB, d4, ctx, q2w, q2b, bufA, h);
    // PHead
    k_conv<ST,128,3,3,1><<<dim3(PXB,32), blk, 0, stream>>>(h,    p1w, p1b, bufA, HD);
    k_conv<ST,128,3,3,0><<<dim3(PXB, 4), blk, 0, stream>>>(bufA, p2w, p2b, lgts, 16);
    k_stats<ST><<<dim3(PXB), blk, 0, stream>>>(lgts, edges, cd, out, it);
  }
}

// ----------------------------------------------------------- launcher ----
extern "C" void kernel_launch(void* const* d_in, const int* in_sizes, int n_in,
                              void* d_out, int out_size, void* d_ws, size_t ws_size,
                              hipStream_t stream){
  const size_t planes = (size_t)(HD + OCH + HD + HD + (BN+1) + BN + BN); // 689
  const size_t need_d = planes * (size_t)BHW * sizeof(double);          // ~212 MB
  if (ws_size >= need_d)
    run_pipeline<double>(d_in, (float*)d_out, (double*)d_ws, stream);
  else
    run_pipeline<float >(d_in, (float*)d_out, (float*)d_ws, stream);
}

// Round 4
// 101437.921 us; speedup vs baseline: 1.5971x; 1.5971x over previous
//
#include <hip/hip_runtime.h>
#include <hip/hip_bf16.h>

// IEBins forward, fp64 math throughout (iter-0 label compare sits on a
// ~6e-5 knife edge; fp32 anywhere in the conv chain flips it — round 2).
// Round 4: out-channel-blocked conv kernels (activations read once per
// kernel, not 32x), weights preconverted to f64 + transposed [c][t][o]
// for wave-uniform s_load_dwordx16 access. Round-3 pipelines kept as
// workspace-size fallback.

#define HD  128
#define CDC 192
#define BN  16
#define OCH 256
#define GC  576
#define NB  2
#define HH  120
#define WW  160
#define HW  (HH*WW)
#define BHW (NB*HW)

// ---------------------------------------------------------------- init ----
template<typename ST>
__global__ __launch_bounds__(256) void k_init(const float* __restrict__ gh,
        ST* __restrict__ h, ST* __restrict__ edges, ST* __restrict__ cd){
  const int i = blockIdx.x*256 + threadIdx.x;
  const int nh = NB*HD*HW;
  if (i < nh) h[i] = (ST)gh[i];
  if (i < BHW){
    const int b = i / HW, r = i - b*HW;
    double e = 0.0;
    #pragma unroll
    for (int k=0;k<BN;++k){
      edges[(b*(BN+1)+k)*HW + r] = (ST)e;
      cd[(b*BN+k)*HW + r] = (ST)(e + 2.5);
      e += 5.0;
    }
    edges[(b*(BN+1)+BN)*HW + r] = (ST)e;   // 80
  }
}

// ------------------------------------------------- weight transpose ------
// w[o][c][tap] f32  ->  wt[(c*TAPS+t)*Cout + o] f64
__global__ __launch_bounds__(256) void k_wxpose(const float* __restrict__ w,
        double* __restrict__ wt, const int Cout, const int CIN, const int TAPS,
        const int n){
  const int i = blockIdx.x*256 + threadIdx.x;
  if (i >= n) return;
  const int ct = CIN*TAPS;
  const int o = i / ct;
  const int rem = i - o*ct;
  const int c = rem / TAPS;
  const int t = rem - c*TAPS;
  wt[((size_t)c*TAPS + t)*Cout + o] = (double)w[i];
}

// ----------------------------------------------- fast generic conv -------
// Block: 256 threads = 4 waves. lane -> pixel (4 px/thread, tile=256 px).
// wave -> out-channel octet. grid.y covers Cout/(4*NACC).
template<int CIN,int KH,int KW,int NACC,int ACT>
__global__ __launch_bounds__(256) void k_fconv(
    const double* __restrict__ in, const double* __restrict__ wt,
    const float* __restrict__ bias, double* __restrict__ out, const int Cout){
  const int lane = threadIdx.x & 63;
  const int wvu  = __builtin_amdgcn_readfirstlane((int)(threadIdx.x >> 6));
  const int ow0  = (blockIdx.y*4 + wvu)*NACC;
  const int pb   = blockIdx.x*256;
  const int b    = pb / HW;
  int rr[4], yy[4], xx[4];
  #pragma unroll
  for (int i=0;i<4;++i){
    const int r = pb + i*64 + lane - b*HW;
    rr[i]=r; yy[i]=r/WW; xx[i]=r - (r/WW)*WW;
  }
  double acc[4][NACC];
  #pragma unroll
  for (int j=0;j<NACC;++j){
    const double bj = (double)bias[ow0+j];
    #pragma unroll
    for (int i=0;i<4;++i) acc[i][j]=bj;
  }
  const double* inb = in + (size_t)b*CIN*HW;
  const int TAPS = KH*KW;
  int dy = -(KH/2), dx = -(KW/2);
  #pragma unroll 1
  for (int t=0;t<TAPS;++t){
    int po[4]; bool va[4];
    #pragma unroll
    for (int i=0;i<4;++i){
      const int iy = yy[i]+dy, ix = xx[i]+dx;
      va[i] = ((unsigned)iy < (unsigned)HH) && ((unsigned)ix < (unsigned)WW);
      po[i] = va[i] ? iy*WW+ix : 0;
    }
    const double* wr = wt + (size_t)t*Cout + ow0;
    #pragma unroll 1
    for (int c=0;c<CIN;++c){
      double v[4];
      #pragma unroll
      for (int i=0;i<4;++i) v[i] = va[i] ? inb[(size_t)c*HW + po[i]] : 0.0;
      #pragma unroll
      for (int j=0;j<NACC;++j){
        const double wj = wr[j];
        #pragma unroll
        for (int i=0;i<4;++i) acc[i][j] = fma(v[i], wj, acc[i][j]);
      }
      wr += (size_t)TAPS*Cout;
    }
    if (++dx > KW/2){ dx = -(KW/2); ++dy; }
  }
  #pragma unroll
  for (int j=0;j<NACC;++j)
    #pragma unroll
    for (int i=0;i<4;++i){
      double v = acc[i][j];
      if (ACT==1) v = v > 0.0 ? v : 0.0;
      out[((size_t)b*Cout + ow0 + j)*HW + rr[i]] = v;
    }
}

// ----------------------------------------------- fast GRU conv -----------
template<typename T,int C,int NACC>
__device__ __forceinline__ void fseg(const T* __restrict__ base,
    const int po[4], const bool va[4], const double* __restrict__ wrow0,
    double acc[4][NACC]){
  const double* wr = wrow0;
  #pragma unroll 1
  for (int c=0;c<C;++c){
    double v[4];
    #pragma unroll
    for (int i=0;i<4;++i) v[i] = va[i] ? (double)base[(size_t)c*HW + po[i]] : 0.0;
    #pragma unroll
    for (int j=0;j<NACC;++j){
      const double wj = wr[j];
      #pragma unroll
      for (int i=0;i<4;++i) acc[i][j] = fma(v[i], wj, acc[i][j]);
    }
    wr += 5*HD;
  }
}

// MODE 0: zg = sigmoid(conv)          (a1=h, hz unused)
// MODE 1: rgh = sigmoid(conv) * h     (a1=h, hz=h)
// MODE 2: h = (1-zg)*h + zg*tanh(conv) (a1=rgh, hz=zg, outp=h)
template<int VERT,int MODE>
__global__ __launch_bounds__(256) void k_fgru(
    const double* __restrict__ a1, const double* __restrict__ d4,
    const float* __restrict__ ctx, const double* __restrict__ wt,
    const float* __restrict__ bias, const double* __restrict__ hz,
    double* __restrict__ outp){
  const int NACC = 8;
  const int lane = threadIdx.x & 63;
  const int wvu  = __builtin_amdgcn_readfirstlane((int)(threadIdx.x >> 6));
  const int ow0  = (blockIdx.y*4 + wvu)*NACC;       // grid.y=4 -> 0..127
  const int pb   = blockIdx.x*256;
  const int b    = pb / HW;
  int rr[4], yy[4], xx[4];
  #pragma unroll
  for (int i=0;i<4;++i){
    const int r = pb + i*64 + lane - b*HW;
    rr[i]=r; yy[i]=r/WW; xx[i]=r - (r/WW)*WW;
  }
  double acc[4][NACC];
  #pragma unroll
  for (int j=0;j<NACC;++j){
    const double bj = (double)bias[ow0+j];
    #pragma unroll
    for (int i=0;i<4;++i) acc[i][j]=bj;
  }
  const double* ab = a1 + (size_t)b*HD *HW;
  const double* db = d4 + (size_t)b*OCH*HW;
  const float*  cb = ctx+ (size_t)b*CDC*HW;
  #pragma unroll 1
  for (int t=0;t<5;++t){
    const int dy = VERT ? (t-2) : 0;
    const int dx = VERT ? 0 : (t-2);
    int po[4]; bool va[4];
    #pragma unroll
    for (int i=0;i<4;++i){
      const int iy = yy[i]+dy, ix = xx[i]+dx;
      va[i] = ((unsigned)iy < (unsigned)HH) && ((unsigned)ix < (unsigned)WW);
      po[i] = va[i] ? iy*WW+ix : 0;
    }
    fseg<double,HD ,NACC>(ab, po, va, wt + ((size_t)0       *5 + t)*HD + ow0, acc);
    fseg<double,OCH,NACC>(db, po, va, wt + ((size_t)HD      *5 + t)*HD + ow0, acc);
    fseg<float ,CDC,NACC>(cb, po, va, wt + ((size_t)(HD+OCH)*5 + t)*HD + ow0, acc);
  }
  #pragma unroll
  for (int j=0;j<NACC;++j)
    #pragma unroll
    for (int i=0;i<4;++i){
      const size_t oi = ((size_t)b*HD + ow0 + j)*HW + rr[i];
      if (MODE==0){
        outp[oi] = 1.0/(1.0+exp(-acc[i][j]));
      } else if (MODE==1){
        outp[oi] = (1.0/(1.0+exp(-acc[i][j]))) * hz[oi];
      } else {
        const double z = hz[oi];
        outp[oi] = (1.0-z)*outp[oi] + z*tanh(acc[i][j]);
      }
    }
}

// ------------------- softmax + depth_r + unc + label + cs + bin update ----
template<typename ST>
__global__ __launch_bounds__(256) void k_stats(const ST* __restrict__ lg,
    ST* __restrict__ edges, ST* __restrict__ cd, float* __restrict__ out,
    const int it){
  const int px = blockIdx.x*256 + threadIdx.x;
  const int b = px / HW, r = px - b*HW;
  double l[BN], p[BN], c[BN];
  double m = -1e300;
  #pragma unroll
  for (int k=0;k<BN;++k){ l[k] = (double)lg[(b*BN+k)*HW + r]; m = l[k]>m?l[k]:m; }
  double s = 0.0;
  #pragma unroll
  for (int k=0;k<BN;++k){ p[k] = exp(l[k]-m); s += p[k]; }
  double dr = 0.0;
  #pragma unroll
  for (int k=0;k<BN;++k){ c[k] = (double)cd[(b*BN+k)*HW + r]; p[k] = p[k]/s; dr += p[k]*c[k]; }
  double var = 0.0;
  #pragma unroll
  for (int k=0;k<BN;++k){ const double d = c[k]-dr; var += p[k]*(d*d); }
  const double un = sqrt(var);
  int cnt = 0;
  #pragma unroll
  for (int k=1;k<BN;++k) cnt += (dr >= (double)edges[(b*(BN+1)+k)*HW + r]) ? 1 : 0;
  const double etop = (double)edges[(b*(BN+1)+BN)*HW + r];
  const int label = (dr >= etop) ? 0 : cnt;
  double csv = c[0];
  #pragma unroll
  for (int k=1;k<BN;++k) csv = (label==k) ? c[k] : csv;
  out[((0*6+it)*NB + b)*HW + r] = (float)dr;
  out[((1*6+it)*NB + b)*HW + r] = (float)csv;
  out[((2*6+it)*NB + b)*HW + r] = (float)un;
  const double start = dr - 0.5*un > 0.0 ? dr - 0.5*un : 0.0;
  const double step = un * (1.0/BN);
  double e = start;
  double prev = e < 0.0 ? 0.0 : (e > 80.0 ? 80.0 : e);
  edges[(b*(BN+1)+0)*HW + r] = (ST)prev;
  #pragma unroll
  for (int k=1;k<=BN;++k){
    e = e + step;
    const double ec = e < 0.0 ? 0.0 : (e > 80.0 ? 80.0 : e);
    edges[(b*(BN+1)+k)*HW + r] = (ST)ec;
    cd[(b*BN + (k-1))*HW + r] = (ST)(0.5*(prev + ec));
    prev = ec;
  }
}

// ======================= round-3 fallback kernels =========================
template<typename ST,int CIN,int KH,int KW,int ACT>
__global__ __launch_bounds__(256) void k_conv(const ST* __restrict__ in,
        const float* __restrict__ w, const float* __restrict__ bias,
        ST* __restrict__ out, const int Cout){
  const int px = blockIdx.x*256 + threadIdx.x;
  const int o0 = blockIdx.y*4;
  const int b = px / HW, r = px - b*HW;
  const int y = r / WW, x = r - y*WW;
  double a0=(double)bias[o0+0], a1=(double)bias[o0+1],
         a2=(double)bias[o0+2], a3=(double)bias[o0+3];
  const ST* inb = in + (size_t)b*CIN*HW;
  const int PH = KH/2, PW = KW/2, WS = CIN*KH*KW;
  #pragma unroll
  for (int dy=0; dy<KH; ++dy){
    const int iy = y + dy - PH;
    if (iy < 0 || iy >= HH) continue;
    #pragma unroll
    for (int dx=0; dx<KW; ++dx){
      const int ix = x + dx - PW;
      if (ix < 0 || ix >= WW) continue;
      const ST* ip = inb + iy*WW + ix;
      const float* wp = w + (size_t)o0*WS + dy*KW + dx;
      for (int c=0; c<CIN; ++c){
        const double v = (double)ip[(size_t)c*HW];
        const int wi = c*KH*KW;
        a0 = fma(v, (double)wp[wi        ], a0);
        a1 = fma(v, (double)wp[wi +   WS ], a1);
        a2 = fma(v, (double)wp[wi + 2*WS ], a2);
        a3 = fma(v, (double)wp[wi + 3*WS ], a3);
      }
    }
  }
  double acc[4] = {a0,a1,a2,a3};
  #pragma unroll
  for (int j=0;j<4;++j){
    double v = acc[j];
    if (ACT==1) v = v > 0.0 ? v : 0.0;
    out[((size_t)b*Cout + o0 + j)*HW + r] = (ST)v;
  }
}

template<int C, typename PT>
__device__ __forceinline__ void acc2(const PT* __restrict__ p,
    const float* __restrict__ wa, const float* __restrict__ wb,
    double aa[4], double ab[4]){
  for (int c=0;c<C;++c){
    const double v = (double)p[(size_t)c*HW];
    const int wi = c*5;
    #pragma unroll
    for (int j=0;j<4;++j){
      aa[j] = fma(v, (double)wa[wi + j*(GC*5)], aa[j]);
      ab[j] = fma(v, (double)wb[wi + j*(GC*5)], ab[j]);
    }
  }
}
template<int C, typename PT>
__device__ __forceinline__ void acc1(const PT* __restrict__ p,
    const float* __restrict__ wa, double aa[4]){
  for (int c=0;c<C;++c){
    const double v = (double)p[(size_t)c*HW];
    const int wi = c*5;
    #pragma unroll
    for (int j=0;j<4;++j) aa[j] = fma(v, (double)wa[wi + j*(GC*5)], aa[j]);
  }
}

template<typename ST,int VERT>
__global__ __launch_bounds__(256) void k_gru_zr(
    const ST* __restrict__ h, const ST* __restrict__ d4, const float* __restrict__ ctx,
    const float* __restrict__ wz, const float* __restrict__ bz,
    const float* __restrict__ wr, const float* __restrict__ br,
    ST* __restrict__ zg, ST* __restrict__ rgh){
  const int px = blockIdx.x*256 + threadIdx.x;
  const int o0 = blockIdx.y*4;
  const int b = px / HW, r = px - b*HW;
  const int y = r / WW, x = r - y*WW;
  double az[4], ar[4];
  #pragma unroll
  for (int j=0;j<4;++j){ az[j]=(double)bz[o0+j]; ar[j]=(double)br[o0+j]; }
  const ST*    hb = h  + (size_t)b*HD *HW;
  const ST*    db = d4 + (size_t)b*OCH*HW;
  const float* cb = ctx+ (size_t)b*CDC*HW;
  #pragma unroll
  for (int k=0;k<5;++k){
    const int iy = VERT ? (y+k-2) : y;
    const int ix = VERT ? x : (x+k-2);
    if (iy<0||iy>=HH||ix<0||ix>=WW) continue;
    const int po = iy*WW + ix;
    const float* wzk = wz + (size_t)o0*GC*5 + k;
    const float* wrk = wr + (size_t)o0*GC*5 + k;
    acc2<HD >(hb+po, wzk,              wrk,              az, ar);
    acc2<OCH>(db+po, wzk + HD*5,       wrk + HD*5,       az, ar);
    acc2<CDC>(cb+po, wzk + (HD+OCH)*5, wrk + (HD+OCH)*5, az, ar);
  }
  #pragma unroll
  for (int j=0;j<4;++j){
    const int oi = (b*HD + o0 + j)*HW + r;
    zg[oi]  = (ST)(1.0/(1.0+exp(-az[j])));
    rgh[oi] = (ST)((1.0/(1.0+exp(-ar[j]))) * (double)h[oi]);
  }
}

template<typename ST,int VERT>
__global__ __launch_bounds__(256) void k_gru_q(
    const ST* __restrict__ rgh, const ST* __restrict__ d4, const float* __restrict__ ctx,
    const float* __restrict__ wq, const float* __restrict__ bq,
    const ST* __restrict__ zg, ST* __restrict__ h){
  const int px = blockIdx.x*256 + threadIdx.x;
  const int o0 = blockIdx.y*4;
  const int b = px / HW, r = px - b*HW;
  const int y = r / WW, x = r - y*WW;
  double aq[4];
  #pragma unroll
  for (int j=0;j<4;++j) aq[j]=(double)bq[o0+j];
  const ST*    gb = rgh + (size_t)b*HD *HW;
  const ST*    db = d4  + (size_t)b*OCH*HW;
  const float* cb = ctx + (size_t)b*CDC*HW;
  #pragma unroll
  for (int k=0;k<5;++k){
    const int iy = VERT ? (y+k-2) : y;
    const int ix = VERT ? x : (x+k-2);
    if (iy<0||iy>=HH||ix<0||ix>=WW) continue;
    const int po = iy*WW + ix;
    const float* wqk = wq + (size_t)o0*GC*5 + k;
    acc1<HD >(gb+po, wqk,              aq);
    acc1<OCH>(db+po, wqk + HD*5,       aq);
    acc1<CDC>(cb+po, wqk + (HD+OCH)*5, aq);
  }
  #pragma unroll
  for (int j=0;j<4;++j){
    const int oi = (b*HD + o0 + j)*HW + r;
    const double q = tanh(aq[j]);
    const double z = (double)zg[oi];
    h[oi] = (ST)((1.0-z)*(double)h[oi] + z*q);
  }
}

template<typename ST>
static void run_pipeline(void* const* d_in, float* out, ST* ws, hipStream_t stream){
  const float* ctx = (const float*)d_in[1];
  const float* gh  = (const float*)d_in[2];
  const float *e1w=(const float*)d_in[3],  *e1b=(const float*)d_in[4];
  const float *e2w=(const float*)d_in[5],  *e2b=(const float*)d_in[6];
  const float *e3w=(const float*)d_in[7],  *e3b=(const float*)d_in[8];
  const float *e4w=(const float*)d_in[9],  *e4b=(const float*)d_in[10];
  const float *z1w=(const float*)d_in[11], *z1b=(const float*)d_in[12];
  const float *r1w=(const float*)d_in[13], *r1b=(const float*)d_in[14];
  const float *q1w=(const float*)d_in[15], *q1b=(const float*)d_in[16];
  const float *z2w=(const float*)d_in[17], *z2b=(const float*)d_in[18];
  const float *r2w=(const float*)d_in[19], *r2b=(const float*)d_in[20];
  const float *q2w=(const float*)d_in[21], *q2b=(const float*)d_in[22];
  const float *p1w=(const float*)d_in[23], *p1b=(const float*)d_in[24];
  const float *p2w=(const float*)d_in[25], *p2b=(const float*)d_in[26];

  ST* h    = ws;
  ST* d4   = h    + (size_t)NB*HD*HW;
  ST* bufA = d4   + (size_t)NB*OCH*HW;
  ST* bufB = bufA + (size_t)NB*HD*HW;
  ST* edges= bufB + (size_t)NB*HD*HW;
  ST* cd   = edges+ (size_t)NB*(BN+1)*HW;
  ST* lgts = cd   + (size_t)NB*BN*HW;

  const dim3 blk(256);
  const int PXB = BHW/256;

  k_init<ST><<<dim3((NB*HD*HW+255)/256), blk, 0, stream>>>(gh, h, edges, cd);

  for (int it=0; it<6; ++it){
    k_conv<ST,16,7,7,1> <<<dim3(PXB,32), blk, 0, stream>>>(cd,   e1w, e1b, bufA, HD);
    k_conv<ST,128,3,3,1><<<dim3(PXB,32), blk, 0, stream>>>(bufA, e2w, e2b, bufB, HD);
    k_conv<ST,128,3,3,1><<<dim3(PXB,32), blk, 0, stream>>>(bufB, e3w, e3b, bufA, HD);
    k_conv<ST,128,3,3,1><<<dim3(PXB,64), blk, 0, stream>>>(bufA, e4w, e4b, d4,  OCH);
    k_gru_zr<ST,0><<<dim3(PXB,32), blk, 0, stream>>>(h, d4, ctx, z1w, z1b, r1w, r1b, bufA, bufB);
    k_gru_q <ST,0><<<dim3(PXB,32), blk, 0, stream>>>(bufB, d4, ctx, q1w, q1b, bufA, h);
    k_gru_zr<ST,1><<<dim3(PXB,32), blk, 0, stream>>>(h, d4, ctx, z2w, z2b, r2w, r2b, bufA, bufB);
    k_gru_q <ST,1><<<dim3(PXB,32), blk, 0, stream>>>(bufB, d4, ctx, q2w, q2b, bufA, h);
    k_conv<ST,128,3,3,1><<<dim3(PXB,32), blk, 0, stream>>>(h,    p1w, p1b, bufA, HD);
    k_conv<ST,128,3,3,0><<<dim3(PXB, 4), blk, 0, stream>>>(bufA, p2w, p2b, lgts, 16);
    k_stats<ST><<<dim3(PXB), blk, 0, stream>>>(lgts, edges, cd, out, it);
  }
}

// ============================ fast pipeline ===============================
static void run_fast(void* const* d_in, float* out, double* ws, hipStream_t stream){
  const float* ctx = (const float*)d_in[1];
  const float* gh  = (const float*)d_in[2];
  const float *e1w=(const float*)d_in[3],  *e1b=(const float*)d_in[4];
  const float *e2w=(const float*)d_in[5],  *e2b=(const float*)d_in[6];
  const float *e3w=(const float*)d_in[7],  *e3b=(const float*)d_in[8];
  const float *e4w=(const float*)d_in[9],  *e4b=(const float*)d_in[10];
  const float *z1w=(const float*)d_in[11], *z1b=(const float*)d_in[12];
  const float *r1w=(const float*)d_in[13], *r1b=(const float*)d_in[14];
  const float *q1w=(const float*)d_in[15], *q1b=(const float*)d_in[16];
  const float *z2w=(const float*)d_in[17], *z2b=(const float*)d_in[18];
  const float *r2w=(const float*)d_in[19], *r2b=(const float*)d_in[20];
  const float *q2w=(const float*)d_in[21], *q2b=(const float*)d_in[22];
  const float *p1w=(const float*)d_in[23], *p1b=(const float*)d_in[24];
  const float *p2w=(const float*)d_in[25], *p2b=(const float*)d_in[26];

  double* h    = ws;
  double* d4   = h    + (size_t)NB*HD*HW;
  double* bufA = d4   + (size_t)NB*OCH*HW;
  double* bufB = bufA + (size_t)NB*HD*HW;
  double* edges= bufB + (size_t)NB*HD*HW;
  double* cd   = edges+ (size_t)NB*(BN+1)*HW;
  double* lgts = cd   + (size_t)NB*BN*HW;
  double* wp   = lgts + (size_t)NB*BN*HW;
  double* we1 = wp;             wp += (size_t)HD*16*49;
  double* we2 = wp;             wp += (size_t)HD*HD*9;
  double* we3 = wp;             wp += (size_t)HD*HD*9;
  double* we4 = wp;             wp += (size_t)OCH*HD*9;
  double* wz1 = wp;             wp += (size_t)HD*GC*5;
  double* wr1 = wp;             wp += (size_t)HD*GC*5;
  double* wq1 = wp;             wp += (size_t)HD*GC*5;
  double* wz2 = wp;             wp += (size_t)HD*GC*5;
  double* wr2 = wp;             wp += (size_t)HD*GC*5;
  double* wq2 = wp;             wp += (size_t)HD*GC*5;
  double* wp1 = wp;             wp += (size_t)HD*HD*9;
  double* wp2 = wp;             wp += (size_t)16*HD*9;

  const dim3 blk(256);
  const int PXB = BHW/256;                      // 150

  // one-time per launch: transpose+f64 weights
  #define XP(src,dst,Cout_,CIN_,TAPS_) { const int n=(Cout_)*(CIN_)*(TAPS_); \
    k_wxpose<<<dim3((n+255)/256), blk, 0, stream>>>(src, dst, Cout_, CIN_, TAPS_, n); }
  XP(e1w, we1, HD, 16, 49); XP(e2w, we2, HD, HD, 9); XP(e3w, we3, HD, HD, 9);
  XP(e4w, we4, OCH, HD, 9);
  XP(z1w, wz1, HD, GC, 5); XP(r1w, wr1, HD, GC, 5); XP(q1w, wq1, HD, GC, 5);
  XP(z2w, wz2, HD, GC, 5); XP(r2w, wr2, HD, GC, 5); XP(q2w, wq2, HD, GC, 5);
  XP(p1w, wp1, HD, HD, 9); XP(p2w, wp2, 16, HD, 9);
  #undef XP

  k_init<double><<<dim3((NB*HD*HW+255)/256), blk, 0, stream>>>(gh, h, edges, cd);

  for (int it=0; it<6; ++it){
    k_fconv<16 ,7,7,8,1><<<dim3(PXB,4), blk, 0, stream>>>(cd,   we1, e1b, bufA, HD);
    k_fconv<128,3,3,8,1><<<dim3(PXB,4), blk, 0, stream>>>(bufA, we2, e2b, bufB, HD);
    k_fconv<128,3,3,8,1><<<dim3(PXB,4), blk, 0, stream>>>(bufB, we3, e3b, bufA, HD);
    k_fconv<128,3,3,8,1><<<dim3(PXB,8), blk, 0, stream>>>(bufA, we4, e4b, d4,  OCH);
    // horizontal GRU
    k_fgru<0,0><<<dim3(PXB,4), blk, 0, stream>>>(h,    d4, ctx, wz1, z1b, h,    bufA);
    k_fgru<0,1><<<dim3(PXB,4), blk, 0, stream>>>(h,    d4, ctx, wr1, r1b, h,    bufB);
    k_fgru<0,2><<<dim3(PXB,4), blk, 0, stream>>>(bufB, d4, ctx, wq1, q1b, bufA, h);
    // vertical GRU
    k_fgru<1,0><<<dim3(PXB,4), blk, 0, stream>>>(h,    d4, ctx, wz2, z2b, h,    bufA);
    k_fgru<1,1><<<dim3(PXB,4), blk, 0, stream>>>(h,    d4, ctx, wr2, r2b, h,    bufB);
    k_fgru<1,2><<<dim3(PXB,4), blk, 0, stream>>>(bufB, d4, ctx, wq2, q2b, bufA, h);
    // PHead
    k_fconv<128,3,3,8,1><<<dim3(PXB,4), blk, 0, stream>>>(h,    wp1, p1b, bufA, HD);
    k_fconv<128,3,3,4,0><<<dim3(PXB,1), blk, 0, stream>>>(bufA, wp2, p2b, lgts, 16);
    k_stats<double><<<dim3(PXB), blk, 0, stream>>>(lgts, edges, cd, out, it);
  }
}

// ----------------------------------------------------------- launcher ----
extern "C" void kernel_launch(void* const* d_in, const int* in_sizes, int n_in,
                              void* d_out, int out_size, void* d_ws, size_t ws_size,
                              hipStream_t stream){
  const size_t act_d  = (size_t)NB*(HD + OCH + HD + HD + (BN+1) + BN + BN)*HW; // doubles
  const size_t wt_d   = (size_t)HD*16*49 + 3*(size_t)HD*HD*9 + (size_t)OCH*HD*9
                      + 6*(size_t)HD*GC*5 + (size_t)16*HD*9;
  const size_t need_fast = (act_d + wt_d) * sizeof(double);   // ~236 MB
  const size_t need_dbl  = act_d * sizeof(double);            // ~212 MB
  if (ws_size >= need_fast)
    run_fast(d_in, (float*)d_out, (double*)d_ws, stream);
  else if (ws_size >= need_dbl)
    run_pipeline<double>(d_in, (float*)d_out, (double*)d_ws, stream);
  else
    run_pipeline<float >(d_in, (float*)d_out, (float*)d_ws, stream);
}

// Round 5
// 69255.872 us; speedup vs baseline: 2.3392x; 1.4647x over previous
//
#include <hip/hip_runtime.h>
#include <hip/hip_bf16.h>

// IEBins forward, fp64 math throughout (iter-0 label compare sits on a
// knife edge; fp32 accumulation flips it — round 2). Round 5: same math /
// same accumulation order as round 4 (bit-identical results), restructured
// for memory behavior:
//   - 2 px/thread -> 1216+ blocks -> ~19 waves/CU (was 9.4, 26% occ)
//   - XCD swizzle: out-channel-group blocks sharing a pixel tile land on
//     the SAME XCD (ids spaced 8 apart) -> activations fetched once/XCD,
//     per-gate weight slice (2.95 MB f64) stays L2-resident.

#define HD  128
#define CDC 192
#define BN  16
#define OCH 256
#define GC  576
#define NB  2
#define HH  120
#define WW  160
#define HW  (HH*WW)
#define BHW (NB*HW)
#define PXT (BHW/128)          // 300 pixel tiles of 128
#define GXP (((PXT+7)/8)*8)    // 304 padded

// ---------------------------------------------------------------- init ----
template<typename ST>
__global__ __launch_bounds__(256) void k_init(const float* __restrict__ gh,
        ST* __restrict__ h, ST* __restrict__ edges, ST* __restrict__ cd){
  const int i = blockIdx.x*256 + threadIdx.x;
  const int nh = NB*HD*HW;
  if (i < nh) h[i] = (ST)gh[i];
  if (i < BHW){
    const int b = i / HW, r = i - b*HW;
    double e = 0.0;
    #pragma unroll
    for (int k=0;k<BN;++k){
      edges[(b*(BN+1)+k)*HW + r] = (ST)e;
      cd[(b*BN+k)*HW + r] = (ST)(e + 2.5);
      e += 5.0;
    }
    edges[(b*(BN+1)+BN)*HW + r] = (ST)e;   // 80
  }
}

// ------------------------------------------------- weight transpose ------
// w[o][c][tap] f32  ->  wt[(c*TAPS+t)*Cout + o] f64
__global__ __launch_bounds__(256) void k_wxpose(const float* __restrict__ w,
        double* __restrict__ wt, const int Cout, const int CIN, const int TAPS,
        const int n){
  const int i = blockIdx.x*256 + threadIdx.x;
  if (i >= n) return;
  const int ct = CIN*TAPS;
  const int o = i / ct;
  const int rem = i - o*ct;
  const int c = rem / TAPS;
  const int t = rem - c*TAPS;
  wt[((size_t)c*TAPS + t)*Cout + o] = (double)w[i];
}

// ------------------------------------------- XCD-aware block decode ------
// 1-D launch of GXP*GY blocks. Blocks with the same pixel tile xs get ids
// spaced 8 apart -> same XCD (id%8 round-robin), co-resident.
template<int GY>
__device__ __forceinline__ bool blk_decode(int& xs, int& yg){
  if (GY == 1){ xs = blockIdx.x; yg = 0; return xs < PXT; }
  const int id = blockIdx.x;
  yg = (id & (8*GY-1)) >> 3;
  const int sh = (GY==4) ? 5 : 6;          // log2(8*GY)
  xs = (id & 7) | ((id >> sh) << 3);
  return xs < PXT;
}

// ----------------------------------------------- fast generic conv -------
// 256 thr = 4 waves; 128-px tile (2 px/thread); wave -> NACC out-channels.
template<int CIN,int KH,int KW,int NACC,int GY,int ACT>
__global__ __launch_bounds__(256) void k_fconv(
    const double* __restrict__ in, const double* __restrict__ wt,
    const float* __restrict__ bias, double* __restrict__ out, const int Cout){
  int xs, yg;
  if (!blk_decode<GY>(xs, yg)) return;
  const int lane = threadIdx.x & 63;
  const int wvu  = __builtin_amdgcn_readfirstlane((int)(threadIdx.x >> 6));
  const int ow0  = (yg*4 + wvu)*NACC;
  const int pb   = xs*128;
  const int b    = pb / HW;
  int rr[2], yy[2], xx[2];
  #pragma unroll
  for (int i=0;i<2;++i){
    const int r = pb + i*64 + lane - b*HW;
    rr[i]=r; yy[i]=r/WW; xx[i]=r - (r/WW)*WW;
  }
  double acc[2][NACC];
  #pragma unroll
  for (int j=0;j<NACC;++j){
    const double bj = (double)bias[ow0+j];
    #pragma unroll
    for (int i=0;i<2;++i) acc[i][j]=bj;
  }
  const double* inb = in + (size_t)b*CIN*HW;
  const int TAPS = KH*KW;
  int dy = -(KH/2), dx = -(KW/2);
  #pragma unroll 1
  for (int t=0;t<TAPS;++t){
    int po[2]; bool va[2];
    #pragma unroll
    for (int i=0;i<2;++i){
      const int iy = yy[i]+dy, ix = xx[i]+dx;
      va[i] = ((unsigned)iy < (unsigned)HH) && ((unsigned)ix < (unsigned)WW);
      po[i] = va[i] ? iy*WW+ix : 0;
    }
    const double* wr = wt + (size_t)t*Cout + ow0;
    #pragma unroll 1
    for (int c=0;c<CIN;++c){
      double v[2];
      #pragma unroll
      for (int i=0;i<2;++i) v[i] = va[i] ? inb[(size_t)c*HW + po[i]] : 0.0;
      #pragma unroll
      for (int j=0;j<NACC;++j){
        const double wj = wr[j];
        #pragma unroll
        for (int i=0;i<2;++i) acc[i][j] = fma(v[i], wj, acc[i][j]);
      }
      wr += (size_t)TAPS*Cout;
    }
    if (++dx > KW/2){ dx = -(KW/2); ++dy; }
  }
  #pragma unroll
  for (int j=0;j<NACC;++j)
    #pragma unroll
    for (int i=0;i<2;++i){
      double v = acc[i][j];
      if (ACT==1) v = v > 0.0 ? v : 0.0;
      out[((size_t)b*Cout + ow0 + j)*HW + rr[i]] = v;
    }
}

// ----------------------------------------------- fast GRU conv -----------
template<typename T,int C,int NACC>
__device__ __forceinline__ void fseg(const T* __restrict__ base,
    const int po[2], const bool va[2], const double* __restrict__ wrow0,
    double acc[2][NACC]){
  const double* wr = wrow0;
  #pragma unroll 1
  for (int c=0;c<C;++c){
    double v[2];
    #pragma unroll
    for (int i=0;i<2;++i) v[i] = va[i] ? (double)base[(size_t)c*HW + po[i]] : 0.0;
    #pragma unroll
    for (int j=0;j<NACC;++j){
      const double wj = wr[j];
      #pragma unroll
      for (int i=0;i<2;++i) acc[i][j] = fma(v[i], wj, acc[i][j]);
    }
    wr += 5*HD;
  }
}

// MODE 0: zg = sigmoid(conv)           (a1=h, hz unused)
// MODE 1: rgh = sigmoid(conv) * h      (a1=h, hz=h)
// MODE 2: h = (1-zg)*h + zg*tanh(conv) (a1=rgh, hz=zg, outp=h)
template<int VERT,int MODE>
__global__ __launch_bounds__(256) void k_fgru(
    const double* __restrict__ a1, const double* __restrict__ d4,
    const float* __restrict__ ctx, const double* __restrict__ wt,
    const float* __restrict__ bias, const double* __restrict__ hz,
    double* __restrict__ outp){
  const int NACC = 8;
  int xs, yg;
  if (!blk_decode<4>(xs, yg)) return;
  const int lane = threadIdx.x & 63;
  const int wvu  = __builtin_amdgcn_readfirstlane((int)(threadIdx.x >> 6));
  const int ow0  = (yg*4 + wvu)*NACC;       // 0..127
  const int pb   = xs*128;
  const int b    = pb / HW;
  int rr[2], yy[2], xx[2];
  #pragma unroll
  for (int i=0;i<2;++i){
    const int r = pb + i*64 + lane - b*HW;
    rr[i]=r; yy[i]=r/WW; xx[i]=r - (r/WW)*WW;
  }
  double acc[2][NACC];
  #pragma unroll
  for (int j=0;j<NACC;++j){
    const double bj = (double)bias[ow0+j];
    #pragma unroll
    for (int i=0;i<2;++i) acc[i][j]=bj;
  }
  const double* ab = a1 + (size_t)b*HD *HW;
  const double* db = d4 + (size_t)b*OCH*HW;
  const float*  cb = ctx+ (size_t)b*CDC*HW;
  #pragma unroll 1
  for (int t=0;t<5;++t){
    const int dy = VERT ? (t-2) : 0;
    const int dx = VERT ? 0 : (t-2);
    int po[2]; bool va[2];
    #pragma unroll
    for (int i=0;i<2;++i){
      const int iy = yy[i]+dy, ix = xx[i]+dx;
      va[i] = ((unsigned)iy < (unsigned)HH) && ((unsigned)ix < (unsigned)WW);
      po[i] = va[i] ? iy*WW+ix : 0;
    }
    fseg<double,HD ,NACC>(ab, po, va, wt + ((size_t)0       *5 + t)*HD + ow0, acc);
    fseg<double,OCH,NACC>(db, po, va, wt + ((size_t)HD      *5 + t)*HD + ow0, acc);
    fseg<float ,CDC,NACC>(cb, po, va, wt + ((size_t)(HD+OCH)*5 + t)*HD + ow0, acc);
  }
  #pragma unroll
  for (int j=0;j<NACC;++j)
    #pragma unroll
    for (int i=0;i<2;++i){
      const size_t oi = ((size_t)b*HD + ow0 + j)*HW + rr[i];
      if (MODE==0){
        outp[oi] = 1.0/(1.0+exp(-acc[i][j]));
      } else if (MODE==1){
        outp[oi] = (1.0/(1.0+exp(-acc[i][j]))) * hz[oi];
      } else {
        const double z = hz[oi];
        outp[oi] = (1.0-z)*outp[oi] + z*tanh(acc[i][j]);
      }
    }
}

// ------------------- softmax + depth_r + unc + label + cs + bin update ----
template<typename ST>
__global__ __launch_bounds__(256) void k_stats(const ST* __restrict__ lg,
    ST* __restrict__ edges, ST* __restrict__ cd, float* __restrict__ out,
    const int it){
  const int px = blockIdx.x*256 + threadIdx.x;
  const int b = px / HW, r = px - b*HW;
  double l[BN], p[BN], c[BN];
  double m = -1e300;
  #pragma unroll
  for (int k=0;k<BN;++k){ l[k] = (double)lg[(b*BN+k)*HW + r]; m = l[k]>m?l[k]:m; }
  double s = 0.0;
  #pragma unroll
  for (int k=0;k<BN;++k){ p[k] = exp(l[k]-m); s += p[k]; }
  double dr = 0.0;
  #pragma unroll
  for (int k=0;k<BN;++k){ c[k] = (double)cd[(b*BN+k)*HW + r]; p[k] = p[k]/s; dr += p[k]*c[k]; }
  double var = 0.0;
  #pragma unroll
  for (int k=0;k<BN;++k){ const double d = c[k]-dr; var += p[k]*(d*d); }
  const double un = sqrt(var);
  int cnt = 0;
  #pragma unroll
  for (int k=1;k<BN;++k) cnt += (dr >= (double)edges[(b*(BN+1)+k)*HW + r]) ? 1 : 0;
  const double etop = (double)edges[(b*(BN+1)+BN)*HW + r];
  const int label = (dr >= etop) ? 0 : cnt;
  double csv = c[0];
  #pragma unroll
  for (int k=1;k<BN;++k) csv = (label==k) ? c[k] : csv;
  out[((0*6+it)*NB + b)*HW + r] = (float)dr;
  out[((1*6+it)*NB + b)*HW + r] = (float)csv;
  out[((2*6+it)*NB + b)*HW + r] = (float)un;
  const double start = dr - 0.5*un > 0.0 ? dr - 0.5*un : 0.0;
  const double step = un * (1.0/BN);
  double e = start;
  double prev = e < 0.0 ? 0.0 : (e > 80.0 ? 80.0 : e);
  edges[(b*(BN+1)+0)*HW + r] = (ST)prev;
  #pragma unroll
  for (int k=1;k<=BN;++k){
    e = e + step;
    const double ec = e < 0.0 ? 0.0 : (e > 80.0 ? 80.0 : e);
    edges[(b*(BN+1)+k)*HW + r] = (ST)ec;
    cd[(b*BN + (k-1))*HW + r] = (ST)(0.5*(prev + ec));
    prev = ec;
  }
}

// ======================= round-3 fallback kernels =========================
template<typename ST,int CIN,int KH,int KW,int ACT>
__global__ __launch_bounds__(256) void k_conv(const ST* __restrict__ in,
        const float* __restrict__ w, const float* __restrict__ bias,
        ST* __restrict__ out, const int Cout){
  const int px = blockIdx.x*256 + threadIdx.x;
  const int o0 = blockIdx.y*4;
  const int b = px / HW, r = px - b*HW;
  const int y = r / WW, x = r - y*WW;
  double a0=(double)bias[o0+0], a1=(double)bias[o0+1],
         a2=(double)bias[o0+2], a3=(double)bias[o0+3];
  const ST* inb = in + (size_t)b*CIN*HW;
  const int PH = KH/2, PW = KW/2, WS = CIN*KH*KW;
  #pragma unroll
  for (int dy=0; dy<KH; ++dy){
    const int iy = y + dy - PH;
    if (iy < 0 || iy >= HH) continue;
    #pragma unroll
    for (int dx=0; dx<KW; ++dx){
      const int ix = x + dx - PW;
      if (ix < 0 || ix >= WW) continue;
      const ST* ip = inb + iy*WW + ix;
      const float* wp = w + (size_t)o0*WS + dy*KW + dx;
      for (int c=0; c<CIN; ++c){
        const double v = (double)ip[(size_t)c*HW];
        const int wi = c*KH*KW;
        a0 = fma(v, (double)wp[wi        ], a0);
        a1 = fma(v, (double)wp[wi +   WS ], a1);
        a2 = fma(v, (double)wp[wi + 2*WS ], a2);
        a3 = fma(v, (double)wp[wi + 3*WS ], a3);
      }
    }
  }
  double acc[4] = {a0,a1,a2,a3};
  #pragma unroll
  for (int j=0;j<4;++j){
    double v = acc[j];
    if (ACT==1) v = v > 0.0 ? v : 0.0;
    out[((size_t)b*Cout + o0 + j)*HW + r] = (ST)v;
  }
}

template<int C, typename PT>
__device__ __forceinline__ void acc2(const PT* __restrict__ p,
    const float* __restrict__ wa, const float* __restrict__ wb,
    double aa[4], double ab[4]){
  for (int c=0;c<C;++c){
    const double v = (double)p[(size_t)c*HW];
    const int wi = c*5;
    #pragma unroll
    for (int j=0;j<4;++j){
      aa[j] = fma(v, (double)wa[wi + j*(GC*5)], aa[j]);
      ab[j] = fma(v, (double)wb[wi + j*(GC*5)], ab[j]);
    }
  }
}
template<int C, typename PT>
__device__ __forceinline__ void acc1(const PT* __restrict__ p,
    const float* __restrict__ wa, double aa[4]){
  for (int c=0;c<C;++c){
    const double v = (double)p[(size_t)c*HW];
    const int wi = c*5;
    #pragma unroll
    for (int j=0;j<4;++j) aa[j] = fma(v, (double)wa[wi + j*(GC*5)], aa[j]);
  }
}

template<typename ST,int VERT>
__global__ __launch_bounds__(256) void k_gru_zr(
    const ST* __restrict__ h, const ST* __restrict__ d4, const float* __restrict__ ctx,
    const float* __restrict__ wz, const float* __restrict__ bz,
    const float* __restrict__ wr, const float* __restrict__ br,
    ST* __restrict__ zg, ST* __restrict__ rgh){
  const int px = blockIdx.x*256 + threadIdx.x;
  const int o0 = blockIdx.y*4;
  const int b = px / HW, r = px - b*HW;
  const int y = r / WW, x = r - y*WW;
  double az[4], ar[4];
  #pragma unroll
  for (int j=0;j<4;++j){ az[j]=(double)bz[o0+j]; ar[j]=(double)br[o0+j]; }
  const ST*    hb = h  + (size_t)b*HD *HW;
  const ST*    db = d4 + (size_t)b*OCH*HW;
  const float* cb = ctx+ (size_t)b*CDC*HW;
  #pragma unroll
  for (int k=0;k<5;++k){
    const int iy = VERT ? (y+k-2) : y;
    const int ix = VERT ? x : (x+k-2);
    if (iy<0||iy>=HH||ix<0||ix>=WW) continue;
    const int po = iy*WW + ix;
    const float* wzk = wz + (size_t)o0*GC*5 + k;
    const float* wrk = wr + (size_t)o0*GC*5 + k;
    acc2<HD >(hb+po, wzk,              wrk,              az, ar);
    acc2<OCH>(db+po, wzk + HD*5,       wrk + HD*5,       az, ar);
    acc2<CDC>(cb+po, wzk + (HD+OCH)*5, wrk + (HD+OCH)*5, az, ar);
  }
  #pragma unroll
  for (int j=0;j<4;++j){
    const int oi = (b*HD + o0 + j)*HW + r;
    zg[oi]  = (ST)(1.0/(1.0+exp(-az[j])));
    rgh[oi] = (ST)((1.0/(1.0+exp(-ar[j]))) * (double)h[oi]);
  }
}

template<typename ST,int VERT>
__global__ __launch_bounds__(256) void k_gru_q(
    const ST* __restrict__ rgh, const ST* __restrict__ d4, const float* __restrict__ ctx,
    const float* __restrict__ wq, const float* __restrict__ bq,
    const ST* __restrict__ zg, ST* __restrict__ h){
  const int px = blockIdx.x*256 + threadIdx.x;
  const int o0 = blockIdx.y*4;
  const int b = px / HW, r = px - b*HW;
  const int y = r / WW, x = r - y*WW;
  double aq[4];
  #pragma unroll
  for (int j=0;j<4;++j) aq[j]=(double)bq[o0+j];
  const ST*    gb = rgh + (size_t)b*HD *HW;
  const ST*    db = d4  + (size_t)b*OCH*HW;
  const float* cb = ctx + (size_t)b*CDC*HW;
  #pragma unroll
  for (int k=0;k<5;++k){
    const int iy = VERT ? (y+k-2) : y;
    const int ix = VERT ? x : (x+k-2);
    if (iy<0||iy>=HH||ix<0||ix>=WW) continue;
    const int po = iy*WW + ix;
    const float* wqk = wq + (size_t)o0*GC*5 + k;
    acc1<HD >(gb+po, wqk,              aq);
    acc1<OCH>(db+po, wqk + HD*5,       aq);
    acc1<CDC>(cb+po, wqk + (HD+OCH)*5, aq);
  }
  #pragma unroll
  for (int j=0;j<4;++j){
    const int oi = (b*HD + o0 + j)*HW + r;
    const double q = tanh(aq[j]);
    const double z = (double)zg[oi];
    h[oi] = (ST)((1.0-z)*(double)h[oi] + z*q);
  }
}

template<typename ST>
static void run_pipeline(void* const* d_in, float* out, ST* ws, hipStream_t stream){
  const float* ctx = (const float*)d_in[1];
  const float* gh  = (const float*)d_in[2];
  const float *e1w=(const float*)d_in[3],  *e1b=(const float*)d_in[4];
  const float *e2w=(const float*)d_in[5],  *e2b=(const float*)d_in[6];
  const float *e3w=(const float*)d_in[7],  *e3b=(const float*)d_in[8];
  const float *e4w=(const float*)d_in[9],  *e4b=(const float*)d_in[10];
  const float *z1w=(const float*)d_in[11], *z1b=(const float*)d_in[12];
  const float *r1w=(const float*)d_in[13], *r1b=(const float*)d_in[14];
  const float *q1w=(const float*)d_in[15], *q1b=(const float*)d_in[16];
  const float *z2w=(const float*)d_in[17], *z2b=(const float*)d_in[18];
  const float *r2w=(const float*)d_in[19], *r2b=(const float*)d_in[20];
  const float *q2w=(const float*)d_in[21], *q2b=(const float*)d_in[22];
  const float *p1w=(const float*)d_in[23], *p1b=(const float*)d_in[24];
  const float *p2w=(const float*)d_in[25], *p2b=(const float*)d_in[26];

  ST* h    = ws;
  ST* d4   = h    + (size_t)NB*HD*HW;
  ST* bufA = d4   + (size_t)NB*OCH*HW;
  ST* bufB = bufA + (size_t)NB*HD*HW;
  ST* edges= bufB + (size_t)NB*HD*HW;
  ST* cd   = edges+ (size_t)NB*(BN+1)*HW;
  ST* lgts = cd   + (size_t)NB*BN*HW;

  const dim3 blk(256);
  const int PXB = BHW/256;

  k_init<ST><<<dim3((NB*HD*HW+255)/256), blk, 0, stream>>>(gh, h, edges, cd);

  for (int it=0; it<6; ++it){
    k_conv<ST,16,7,7,1> <<<dim3(PXB,32), blk, 0, stream>>>(cd,   e1w, e1b, bufA, HD);
    k_conv<ST,128,3,3,1><<<dim3(PXB,32), blk, 0, stream>>>(bufA, e2w, e2b, bufB, HD);
    k_conv<ST,128,3,3,1><<<dim3(PXB,32), blk, 0, stream>>>(bufB, e3w, e3b, bufA, HD);
    k_conv<ST,128,3,3,1><<<dim3(PXB,64), blk, 0, stream>>>(bufA, e4w, e4b, d4,  OCH);
    k_gru_zr<ST,0><<<dim3(PXB,32), blk, 0, stream>>>(h, d4, ctx, z1w, z1b, r1w, r1b, bufA, bufB);
    k_gru_q <ST,0><<<dim3(PXB,32), blk, 0, stream>>>(bufB, d4, ctx, q1w, q1b, bufA, h);
    k_gru_zr<ST,1><<<dim3(PXB,32), blk, 0, stream>>>(h, d4, ctx, z2w, z2b, r2w, r2b, bufA, bufB);
    k_gru_q <ST,1><<<dim3(PXB,32), blk, 0, stream>>>(bufB, d4, ctx, q2w, q2b, bufA, h);
    k_conv<ST,128,3,3,1><<<dim3(PXB,32), blk, 0, stream>>>(h,    p1w, p1b, bufA, HD);
    k_conv<ST,128,3,3,0><<<dim3(PXB, 4), blk, 0, stream>>>(bufA, p2w, p2b, lgts, 16);
    k_stats<ST><<<dim3(PXB), blk, 0, stream>>>(lgts, edges, cd, out, it);
  }
}

// ============================ fast pipeline ===============================
static void run_fast(void* const* d_in, float* out, double* ws, hipStream_t stream){
  const float* ctx = (const float*)d_in[1];
  const float* gh  = (const float*)d_in[2];
  const float *e1w=(const float*)d_in[3],  *e1b=(const float*)d_in[4];
  const float *e2w=(const float*)d_in[5],  *e2b=(const float*)d_in[6];
  const float *e3w=(const float*)d_in[7],  *e3b=(const float*)d_in[8];
  const float *e4w=(const float*)d_in[9],  *e4b=(const float*)d_in[10];
  const float *z1w=(const float*)d_in[11], *z1b=(const float*)d_in[12];
  const float *r1w=(const float*)d_in[13], *r1b=(const float*)d_in[14];
  const float *q1w=(const float*)d_in[15], *q1b=(const float*)d_in[16];
  const float *z2w=(const float*)d_in[17], *z2b=(const float*)d_in[18];
  const float *r2w=(const float*)d_in[19], *r2b=(const float*)d_in[20];
  const float *q2w=(const float*)d_in[21], *q2b=(const float*)d_in[22];
  const float *p1w=(const float*)d_in[23], *p1b=(const float*)d_in[24];
  const float *p2w=(const float*)d_in[25], *p2b=(const float*)d_in[26];

  double* h    = ws;
  double* d4   = h    + (size_t)NB*HD*HW;
  double* bufA = d4   + (size_t)NB*OCH*HW;
  double* bufB = bufA + (size_t)NB*HD*HW;
  double* edges= bufB + (size_t)NB*HD*HW;
  double* cd   = edges+ (size_t)NB*(BN+1)*HW;
  double* lgts = cd   + (size_t)NB*BN*HW;
  double* wp   = lgts + (size_t)NB*BN*HW;
  double* we1 = wp;             wp += (size_t)HD*16*49;
  double* we2 = wp;             wp += (size_t)HD*HD*9;
  double* we3 = wp;             wp += (size_t)HD*HD*9;
  double* we4 = wp;             wp += (size_t)OCH*HD*9;
  double* wz1 = wp;             wp += (size_t)HD*GC*5;
  double* wr1 = wp;             wp += (size_t)HD*GC*5;
  double* wq1 = wp;             wp += (size_t)HD*GC*5;
  double* wz2 = wp;             wp += (size_t)HD*GC*5;
  double* wr2 = wp;             wp += (size_t)HD*GC*5;
  double* wq2 = wp;             wp += (size_t)HD*GC*5;
  double* wp1 = wp;             wp += (size_t)HD*HD*9;
  double* wp2 = wp;             wp += (size_t)16*HD*9;

  const dim3 blk(256);

  // one-time per launch: transpose+f64 weights
  #define XP(src,dst,Cout_,CIN_,TAPS_) { const int n=(Cout_)*(CIN_)*(TAPS_); \
    k_wxpose<<<dim3((n+255)/256), blk, 0, stream>>>(src, dst, Cout_, CIN_, TAPS_, n); }
  XP(e1w, we1, HD, 16, 49); XP(e2w, we2, HD, HD, 9); XP(e3w, we3, HD, HD, 9);
  XP(e4w, we4, OCH, HD, 9);
  XP(z1w, wz1, HD, GC, 5); XP(r1w, wr1, HD, GC, 5); XP(q1w, wq1, HD, GC, 5);
  XP(z2w, wz2, HD, GC, 5); XP(r2w, wr2, HD, GC, 5); XP(q2w, wq2, HD, GC, 5);
  XP(p1w, wp1, HD, HD, 9); XP(p2w, wp2, 16, HD, 9);
  #undef XP

  k_init<double><<<dim3((NB*HD*HW+255)/256), blk, 0, stream>>>(gh, h, edges, cd);

  const int G4 = GXP*4;    // swizzled 1-D grids
  const int G8 = GXP*8;
  const int PXB = BHW/256; // for stats

  for (int it=0; it<6; ++it){
    k_fconv<16 ,7,7,8,4,1><<<dim3(G4), blk, 0, stream>>>(cd,   we1, e1b, bufA, HD);
    k_fconv<128,3,3,8,4,1><<<dim3(G4), blk, 0, stream>>>(bufA, we2, e2b, bufB, HD);
    k_fconv<128,3,3,8,4,1><<<dim3(G4), blk, 0, stream>>>(bufB, we3, e3b, bufA, HD);
    k_fconv<128,3,3,8,8,1><<<dim3(G8), blk, 0, stream>>>(bufA, we4, e4b, d4,  OCH);
    // horizontal GRU
    k_fgru<0,0><<<dim3(G4), blk, 0, stream>>>(h,    d4, ctx, wz1, z1b, h,    bufA);
    k_fgru<0,1><<<dim3(G4), blk, 0, stream>>>(h,    d4, ctx, wr1, r1b, h,    bufB);
    k_fgru<0,2><<<dim3(G4), blk, 0, stream>>>(bufB, d4, ctx, wq1, q1b, bufA, h);
    // vertical GRU
    k_fgru<1,0><<<dim3(G4), blk, 0, stream>>>(h,    d4, ctx, wz2, z2b, h,    bufA);
    k_fgru<1,1><<<dim3(G4), blk, 0, stream>>>(h,    d4, ctx, wr2, r2b, h,    bufB);
    k_fgru<1,2><<<dim3(G4), blk, 0, stream>>>(bufB, d4, ctx, wq2, q2b, bufA, h);
    // PHead
    k_fconv<128,3,3,8,4,1><<<dim3(G4),  blk, 0, stream>>>(h,    wp1, p1b, bufA, HD);
    k_fconv<128,3,3,4,1,0><<<dim3(PXT), blk, 0, stream>>>(bufA, wp2, p2b, lgts, 16);
    k_stats<double><<<dim3(PXB), blk, 0, stream>>>(lgts, edges, cd, out, it);
  }
}

// ----------------------------------------------------------- launcher ----
extern "C" void kernel_launch(void* const* d_in, const int* in_sizes, int n_in,
                              void* d_out, int out_size, void* d_ws, size_t ws_size,
                              hipStream_t stream){
  const size_t act_d  = (size_t)NB*(HD + OCH + HD + HD + (BN+1) + BN + BN)*HW; // doubles
  const size_t wt_d   = (size_t)HD*16*49 + 3*(size_t)HD*HD*9 + (size_t)OCH*HD*9
                      + 6*(size_t)HD*GC*5 + (size_t)16*HD*9;
  const size_t need_fast = (act_d + wt_d) * sizeof(double);   // ~236 MB
  const size_t need_dbl  = act_d * sizeof(double);            // ~212 MB
  if (ws_size >= need_fast)
    run_fast(d_in, (float*)d_out, (double*)d_ws, stream);
  else if (ws_size >= need_dbl)
    run_pipeline<double>(d_in, (float*)d_out, (double*)d_ws, stream);
  else
    run_pipeline<float >(d_in, (float*)d_out, (float*)d_ws, stream);
}

// Round 6
// 45936.740 us; speedup vs baseline: 3.5267x; 1.5076x over previous
//
#include <hip/hip_runtime.h>
#include <hip/hip_bf16.h>

// IEBins forward, fp64 math throughout (iter-0 label compare sits on a
// knife edge; fp32 accumulation flips it — round 2). Round 6: attack the
// latency-bound GRU convs (VALUBusy 33%, HBM 4% in round 5):
//   - z+r fused in one kernel: every activation load feeds 2 gates
//     (32 f64 FMA per 2 loads) -> compute-saturated.
//   - q kernel + fconv channel loops: #pragma unroll 4 -> 8 loads in
//     flight/wave instead of 2.
//   - per-gate fp64 accumulation chains unchanged -> bit-identical to
//     round 5 (absmax stays 1.0).

#define HD  128
#define CDC 192
#define BN  16
#define OCH 256
#define GC  576
#define NB  2
#define HH  120
#define WW  160
#define HW  (HH*WW)
#define BHW (NB*HW)
#define PXT (BHW/128)          // 300 pixel tiles of 128
#define GXP (((PXT+7)/8)*8)    // 304 padded

// ---------------------------------------------------------------- init ----
template<typename ST>
__global__ __launch_bounds__(256) void k_init(const float* __restrict__ gh,
        ST* __restrict__ h, ST* __restrict__ edges, ST* __restrict__ cd){
  const int i = blockIdx.x*256 + threadIdx.x;
  const int nh = NB*HD*HW;
  if (i < nh) h[i] = (ST)gh[i];
  if (i < BHW){
    const int b = i / HW, r = i - b*HW;
    double e = 0.0;
    #pragma unroll
    for (int k=0;k<BN;++k){
      edges[(b*(BN+1)+k)*HW + r] = (ST)e;
      cd[(b*BN+k)*HW + r] = (ST)(e + 2.5);
      e += 5.0;
    }
    edges[(b*(BN+1)+BN)*HW + r] = (ST)e;   // 80
  }
}

// ------------------------------------------------- weight transpose ------
// w[o][c][tap] f32  ->  wt[(c*TAPS+t)*Cout + o] f64
__global__ __launch_bounds__(256) void k_wxpose(const float* __restrict__ w,
        double* __restrict__ wt, const int Cout, const int CIN, const int TAPS,
        const int n){
  const int i = blockIdx.x*256 + threadIdx.x;
  if (i >= n) return;
  const int ct = CIN*TAPS;
  const int o = i / ct;
  const int rem = i - o*ct;
  const int c = rem / TAPS;
  const int t = rem - c*TAPS;
  wt[((size_t)c*TAPS + t)*Cout + o] = (double)w[i];
}

// ------------------------------------------- XCD-aware block decode ------
template<int GY>
__device__ __forceinline__ bool blk_decode(int& xs, int& yg){
  if (GY == 1){ xs = blockIdx.x; yg = 0; return xs < PXT; }
  const int id = blockIdx.x;
  yg = (id & (8*GY-1)) >> 3;
  const int sh = (GY==4) ? 5 : 6;          // log2(8*GY)
  xs = (id & 7) | ((id >> sh) << 3);
  return xs < PXT;
}

// ----------------------------------------------- fast generic conv -------
// 256 thr = 4 waves; 128-px tile (2 px/thread); wave -> NACC out-channels.
template<int CIN,int KH,int KW,int NACC,int GY,int ACT>
__global__ __launch_bounds__(256) void k_fconv(
    const double* __restrict__ in, const double* __restrict__ wt,
    const float* __restrict__ bias, double* __restrict__ out, const int Cout){
  int xs, yg;
  if (!blk_decode<GY>(xs, yg)) return;
  const int lane = threadIdx.x & 63;
  const int wvu  = __builtin_amdgcn_readfirstlane((int)(threadIdx.x >> 6));
  const int ow0  = (yg*4 + wvu)*NACC;
  const int pb   = xs*128;
  const int b    = pb / HW;
  int rr[2], yy[2], xx[2];
  #pragma unroll
  for (int i=0;i<2;++i){
    const int r = pb + i*64 + lane - b*HW;
    rr[i]=r; yy[i]=r/WW; xx[i]=r - (r/WW)*WW;
  }
  double acc[2][NACC];
  #pragma unroll
  for (int j=0;j<NACC;++j){
    const double bj = (double)bias[ow0+j];
    #pragma unroll
    for (int i=0;i<2;++i) acc[i][j]=bj;
  }
  const double* inb = in + (size_t)b*CIN*HW;
  const int TAPS = KH*KW;
  int dy = -(KH/2), dx = -(KW/2);
  #pragma unroll 1
  for (int t=0;t<TAPS;++t){
    int po[2]; bool va[2];
    #pragma unroll
    for (int i=0;i<2;++i){
      const int iy = yy[i]+dy, ix = xx[i]+dx;
      va[i] = ((unsigned)iy < (unsigned)HH) && ((unsigned)ix < (unsigned)WW);
      po[i] = va[i] ? iy*WW+ix : 0;
    }
    const double* wr = wt + (size_t)t*Cout + ow0;
    #pragma unroll 4
    for (int c=0;c<CIN;++c){
      double v[2];
      #pragma unroll
      for (int i=0;i<2;++i) v[i] = va[i] ? inb[(size_t)c*HW + po[i]] : 0.0;
      #pragma unroll
      for (int j=0;j<NACC;++j){
        const double wj = wr[j];
        #pragma unroll
        for (int i=0;i<2;++i) acc[i][j] = fma(v[i], wj, acc[i][j]);
      }
      wr += (size_t)TAPS*Cout;
    }
    if (++dx > KW/2){ dx = -(KW/2); ++dy; }
  }
  #pragma unroll
  for (int j=0;j<NACC;++j)
    #pragma unroll
    for (int i=0;i<2;++i){
      double v = acc[i][j];
      if (ACT==1) v = v > 0.0 ? v : 0.0;
      out[((size_t)b*Cout + ow0 + j)*HW + rr[i]] = v;
    }
}

// -------------------------------------------- GRU conv segment helpers ---
// Two-gate accumulate (z,r) — every load feeds 32 f64 FMAs.
template<typename T,int C,int NACC>
__device__ __forceinline__ void fseg2(const T* __restrict__ base,
    const int po[2], const bool va[2],
    const double* __restrict__ wz0, const double* __restrict__ wr0,
    double az[2][NACC], double ar[2][NACC]){
  const double* wz = wz0;
  const double* wr = wr0;
  #pragma unroll 2
  for (int c=0;c<C;++c){
    double v[2];
    #pragma unroll
    for (int i=0;i<2;++i) v[i] = va[i] ? (double)base[(size_t)c*HW + po[i]] : 0.0;
    #pragma unroll
    for (int j=0;j<NACC;++j){
      const double wzj = wz[j], wrj = wr[j];
      #pragma unroll
      for (int i=0;i<2;++i){
        az[i][j] = fma(v[i], wzj, az[i][j]);
        ar[i][j] = fma(v[i], wrj, ar[i][j]);
      }
    }
    wz += 5*HD; wr += 5*HD;
  }
}
// One-gate accumulate (q) — unroll 4 for load ILP.
template<typename T,int C,int NACC>
__device__ __forceinline__ void fseg1(const T* __restrict__ base,
    const int po[2], const bool va[2], const double* __restrict__ wq0,
    double aq[2][NACC]){
  const double* wq = wq0;
  #pragma unroll 4
  for (int c=0;c<C;++c){
    double v[2];
    #pragma unroll
    for (int i=0;i<2;++i) v[i] = va[i] ? (double)base[(size_t)c*HW + po[i]] : 0.0;
    #pragma unroll
    for (int j=0;j<NACC;++j){
      const double wj = wq[j];
      #pragma unroll
      for (int i=0;i<2;++i) aq[i][j] = fma(v[i], wj, aq[i][j]);
    }
    wq += 5*HD;
  }
}

// Fused z,r conv: zg = sigmoid(z_conv); rgh = sigmoid(r_conv) * h.
template<int VERT>
__global__ __launch_bounds__(256) void k_fgru_zr(
    const double* __restrict__ h, const double* __restrict__ d4,
    const float* __restrict__ ctx,
    const double* __restrict__ wtz, const double* __restrict__ wtr,
    const float* __restrict__ bz, const float* __restrict__ br,
    double* __restrict__ zg, double* __restrict__ rgh){
  const int NACC = 8;
  int xs, yg;
  if (!blk_decode<4>(xs, yg)) return;
  const int lane = threadIdx.x & 63;
  const int wvu  = __builtin_amdgcn_readfirstlane((int)(threadIdx.x >> 6));
  const int ow0  = (yg*4 + wvu)*NACC;       // 0..127
  const int pb   = xs*128;
  const int b    = pb / HW;
  int rr[2], yy[2], xx[2];
  #pragma unroll
  for (int i=0;i<2;++i){
    const int r = pb + i*64 + lane - b*HW;
    rr[i]=r; yy[i]=r/WW; xx[i]=r - (r/WW)*WW;
  }
  double az[2][NACC], ar[2][NACC];
  #pragma unroll
  for (int j=0;j<NACC;++j){
    const double bzj = (double)bz[ow0+j], brj = (double)br[ow0+j];
    #pragma unroll
    for (int i=0;i<2;++i){ az[i][j]=bzj; ar[i][j]=brj; }
  }
  const double* ab = h  + (size_t)b*HD *HW;
  const double* db = d4 + (size_t)b*OCH*HW;
  const float*  cb = ctx+ (size_t)b*CDC*HW;
  #pragma unroll 1
  for (int t=0;t<5;++t){
    const int dy = VERT ? (t-2) : 0;
    const int dx = VERT ? 0 : (t-2);
    int po[2]; bool va[2];
    #pragma unroll
    for (int i=0;i<2;++i){
      const int iy = yy[i]+dy, ix = xx[i]+dx;
      va[i] = ((unsigned)iy < (unsigned)HH) && ((unsigned)ix < (unsigned)WW);
      po[i] = va[i] ? iy*WW+ix : 0;
    }
    fseg2<double,HD ,NACC>(ab, po, va,
        wtz + ((size_t)0*5 + t)*HD + ow0,        wtr + ((size_t)0*5 + t)*HD + ow0, az, ar);
    fseg2<double,OCH,NACC>(db, po, va,
        wtz + ((size_t)HD*5 + t)*HD + ow0,       wtr + ((size_t)HD*5 + t)*HD + ow0, az, ar);
    fseg2<float ,CDC,NACC>(cb, po, va,
        wtz + ((size_t)(HD+OCH)*5 + t)*HD + ow0, wtr + ((size_t)(HD+OCH)*5 + t)*HD + ow0, az, ar);
  }
  #pragma unroll
  for (int j=0;j<NACC;++j)
    #pragma unroll
    for (int i=0;i<2;++i){
      const size_t oi = ((size_t)b*HD + ow0 + j)*HW + rr[i];
      zg[oi]  = 1.0/(1.0+exp(-az[i][j]));
      rgh[oi] = (1.0/(1.0+exp(-ar[i][j]))) * h[oi];
    }
}

// q conv + in-place hidden update: h = (1-zg)*h + zg*tanh(conv).
template<int VERT>
__global__ __launch_bounds__(256) void k_fgru_q(
    const double* __restrict__ rgh, const double* __restrict__ d4,
    const float* __restrict__ ctx, const double* __restrict__ wtq,
    const float* __restrict__ bq, const double* __restrict__ zg,
    double* __restrict__ h){
  const int NACC = 8;
  int xs, yg;
  if (!blk_decode<4>(xs, yg)) return;
  const int lane = threadIdx.x & 63;
  const int wvu  = __builtin_amdgcn_readfirstlane((int)(threadIdx.x >> 6));
  const int ow0  = (yg*4 + wvu)*NACC;
  const int pb   = xs*128;
  const int b    = pb / HW;
  int rr[2], yy[2], xx[2];
  #pragma unroll
  for (int i=0;i<2;++i){
    const int r = pb + i*64 + lane - b*HW;
    rr[i]=r; yy[i]=r/WW; xx[i]=r - (r/WW)*WW;
  }
  double aq[2][NACC];
  #pragma unroll
  for (int j=0;j<NACC;++j){
    const double bj = (double)bq[ow0+j];
    #pragma unroll
    for (int i=0;i<2;++i) aq[i][j]=bj;
  }
  const double* gb = rgh + (size_t)b*HD *HW;
  const double* db = d4  + (size_t)b*OCH*HW;
  const float*  cb = ctx + (size_t)b*CDC*HW;
  #pragma unroll 1
  for (int t=0;t<5;++t){
    const int dy = VERT ? (t-2) : 0;
    const int dx = VERT ? 0 : (t-2);
    int po[2]; bool va[2];
    #pragma unroll
    for (int i=0;i<2;++i){
      const int iy = yy[i]+dy, ix = xx[i]+dx;
      va[i] = ((unsigned)iy < (unsigned)HH) && ((unsigned)ix < (unsigned)WW);
      po[i] = va[i] ? iy*WW+ix : 0;
    }
    fseg1<double,HD ,NACC>(gb, po, va, wtq + ((size_t)0       *5 + t)*HD + ow0, aq);
    fseg1<double,OCH,NACC>(db, po, va, wtq + ((size_t)HD      *5 + t)*HD + ow0, aq);
    fseg1<float ,CDC,NACC>(cb, po, va, wtq + ((size_t)(HD+OCH)*5 + t)*HD + ow0, aq);
  }
  #pragma unroll
  for (int j=0;j<NACC;++j)
    #pragma unroll
    for (int i=0;i<2;++i){
      const size_t oi = ((size_t)b*HD + ow0 + j)*HW + rr[i];
      const double z = zg[oi];
      h[oi] = (1.0-z)*h[oi] + z*tanh(aq[i][j]);
    }
}

// ------------------- softmax + depth_r + unc + label + cs + bin update ----
template<typename ST>
__global__ __launch_bounds__(256) void k_stats(const ST* __restrict__ lg,
    ST* __restrict__ edges, ST* __restrict__ cd, float* __restrict__ out,
    const int it){
  const int px = blockIdx.x*256 + threadIdx.x;
  const int b = px / HW, r = px - b*HW;
  double l[BN], p[BN], c[BN];
  double m = -1e300;
  #pragma unroll
  for (int k=0;k<BN;++k){ l[k] = (double)lg[(b*BN+k)*HW + r]; m = l[k]>m?l[k]:m; }
  double s = 0.0;
  #pragma unroll
  for (int k=0;k<BN;++k){ p[k] = exp(l[k]-m); s += p[k]; }
  double dr = 0.0;
  #pragma unroll
  for (int k=0;k<BN;++k){ c[k] = (double)cd[(b*BN+k)*HW + r]; p[k] = p[k]/s; dr += p[k]*c[k]; }
  double var = 0.0;
  #pragma unroll
  for (int k=0;k<BN;++k){ const double d = c[k]-dr; var += p[k]*(d*d); }
  const double un = sqrt(var);
  int cnt = 0;
  #pragma unroll
  for (int k=1;k<BN;++k) cnt += (dr >= (double)edges[(b*(BN+1)+k)*HW + r]) ? 1 : 0;
  const double etop = (double)edges[(b*(BN+1)+BN)*HW + r];
  const int label = (dr >= etop) ? 0 : cnt;
  double csv = c[0];
  #pragma unroll
  for (int k=1;k<BN;++k) csv = (label==k) ? c[k] : csv;
  out[((0*6+it)*NB + b)*HW + r] = (float)dr;
  out[((1*6+it)*NB + b)*HW + r] = (float)csv;
  out[((2*6+it)*NB + b)*HW + r] = (float)un;
  const double start = dr - 0.5*un > 0.0 ? dr - 0.5*un : 0.0;
  const double step = un * (1.0/BN);
  double e = start;
  double prev = e < 0.0 ? 0.0 : (e > 80.0 ? 80.0 : e);
  edges[(b*(BN+1)+0)*HW + r] = (ST)prev;
  #pragma unroll
  for (int k=1;k<=BN;++k){
    e = e + step;
    const double ec = e < 0.0 ? 0.0 : (e > 80.0 ? 80.0 : e);
    edges[(b*(BN+1)+k)*HW + r] = (ST)ec;
    cd[(b*BN + (k-1))*HW + r] = (ST)(0.5*(prev + ec));
    prev = ec;
  }
}

// ======================= round-3 fallback kernels =========================
template<typename ST,int CIN,int KH,int KW,int ACT>
__global__ __launch_bounds__(256) void k_conv(const ST* __restrict__ in,
        const float* __restrict__ w, const float* __restrict__ bias,
        ST* __restrict__ out, const int Cout){
  const int px = blockIdx.x*256 + threadIdx.x;
  const int o0 = blockIdx.y*4;
  const int b = px / HW, r = px - b*HW;
  const int y = r / WW, x = r - y*WW;
  double a0=(double)bias[o0+0], a1=(double)bias[o0+1],
         a2=(double)bias[o0+2], a3=(double)bias[o0+3];
  const ST* inb = in + (size_t)b*CIN*HW;
  const int PH = KH/2, PW = KW/2, WS = CIN*KH*KW;
  #pragma unroll
  for (int dy=0; dy<KH; ++dy){
    const int iy = y + dy - PH;
    if (iy < 0 || iy >= HH) continue;
    #pragma unroll
    for (int dx=0; dx<KW; ++dx){
      const int ix = x + dx - PW;
      if (ix < 0 || ix >= WW) continue;
      const ST* ip = inb + iy*WW + ix;
      const float* wp = w + (size_t)o0*WS + dy*KW + dx;
      for (int c=0; c<CIN; ++c){
        const double v = (double)ip[(size_t)c*HW];
        const int wi = c*KH*KW;
        a0 = fma(v, (double)wp[wi        ], a0);
        a1 = fma(v, (double)wp[wi +   WS ], a1);
        a2 = fma(v, (double)wp[wi + 2*WS ], a2);
        a3 = fma(v, (double)wp[wi + 3*WS ], a3);
      }
    }
  }
  double acc[4] = {a0,a1,a2,a3};
  #pragma unroll
  for (int j=0;j<4;++j){
    double v = acc[j];
    if (ACT==1) v = v > 0.0 ? v : 0.0;
    out[((size_t)b*Cout + o0 + j)*HW + r] = (ST)v;
  }
}

template<int C, typename PT>
__device__ __forceinline__ void acc2(const PT* __restrict__ p,
    const float* __restrict__ wa, const float* __restrict__ wb,
    double aa[4], double ab[4]){
  for (int c=0;c<C;++c){
    const double v = (double)p[(size_t)c*HW];
    const int wi = c*5;
    #pragma unroll
    for (int j=0;j<4;++j){
      aa[j] = fma(v, (double)wa[wi + j*(GC*5)], aa[j]);
      ab[j] = fma(v, (double)wb[wi + j*(GC*5)], ab[j]);
    }
  }
}
template<int C, typename PT>
__device__ __forceinline__ void acc1(const PT* __restrict__ p,
    const float* __restrict__ wa, double aa[4]){
  for (int c=0;c<C;++c){
    const double v = (double)p[(size_t)c*HW];
    const int wi = c*5;
    #pragma unroll
    for (int j=0;j<4;++j) aa[j] = fma(v, (double)wa[wi + j*(GC*5)], aa[j]);
  }
}

template<typename ST,int VERT>
__global__ __launch_bounds__(256) void k_gru_zr(
    const ST* __restrict__ h, const ST* __restrict__ d4, const float* __restrict__ ctx,
    const float* __restrict__ wz, const float* __restrict__ bz,
    const float* __restrict__ wr, const float* __restrict__ br,
    ST* __restrict__ zg, ST* __restrict__ rgh){
  const int px = blockIdx.x*256 + threadIdx.x;
  const int o0 = blockIdx.y*4;
  const int b = px / HW, r = px - b*HW;
  const int y = r / WW, x = r - y*WW;
  double az[4], ar[4];
  #pragma unroll
  for (int j=0;j<4;++j){ az[j]=(double)bz[o0+j]; ar[j]=(double)br[o0+j]; }
  const ST*    hb = h  + (size_t)b*HD *HW;
  const ST*    db = d4 + (size_t)b*OCH*HW;
  const float* cb = ctx+ (size_t)b*CDC*HW;
  #pragma unroll
  for (int k=0;k<5;++k){
    const int iy = VERT ? (y+k-2) : y;
    const int ix = VERT ? x : (x+k-2);
    if (iy<0||iy>=HH||ix<0||ix>=WW) continue;
    const int po = iy*WW + ix;
    const float* wzk = wz + (size_t)o0*GC*5 + k;
    const float* wrk = wr + (size_t)o0*GC*5 + k;
    acc2<HD >(hb+po, wzk,              wrk,              az, ar);
    acc2<OCH>(db+po, wzk + HD*5,       wrk + HD*5,       az, ar);
    acc2<CDC>(cb+po, wzk + (HD+OCH)*5, wrk + (HD+OCH)*5, az, ar);
  }
  #pragma unroll
  for (int j=0;j<4;++j){
    const int oi = (b*HD + o0 + j)*HW + r;
    zg[oi]  = (ST)(1.0/(1.0+exp(-az[j])));
    rgh[oi] = (ST)((1.0/(1.0+exp(-ar[j]))) * (double)h[oi]);
  }
}

template<typename ST,int VERT>
__global__ __launch_bounds__(256) void k_gru_q(
    const ST* __restrict__ rgh, const ST* __restrict__ d4, const float* __restrict__ ctx,
    const float* __restrict__ wq, const float* __restrict__ bq,
    const ST* __restrict__ zg, ST* __restrict__ h){
  const int px = blockIdx.x*256 + threadIdx.x;
  const int o0 = blockIdx.y*4;
  const int b = px / HW, r = px - b*HW;
  const int y = r / WW, x = r - y*WW;
  double aq[4];
  #pragma unroll
  for (int j=0;j<4;++j) aq[j]=(double)bq[o0+j];
  const ST*    gb = rgh + (size_t)b*HD *HW;
  const ST*    db = d4  + (size_t)b*OCH*HW;
  const float* cb = ctx + (size_t)b*CDC*HW;
  #pragma unroll
  for (int k=0;k<5;++k){
    const int iy = VERT ? (y+k-2) : y;
    const int ix = VERT ? x : (x+k-2);
    if (iy<0||iy>=HH||ix<0||ix>=WW) continue;
    const int po = iy*WW + ix;
    const float* wqk = wq + (size_t)o0*GC*5 + k;
    acc1<HD >(gb+po, wqk,              aq);
    acc1<OCH>(db+po, wqk + HD*5,       aq);
    acc1<CDC>(cb+po, wqk + (HD+OCH)*5, aq);
  }
  #pragma unroll
  for (int j=0;j<4;++j){
    const int oi = (b*HD + o0 + j)*HW + r;
    const double q = tanh(aq[j]);
    const double z = (double)zg[oi];
    h[oi] = (ST)((1.0-z)*(double)h[oi] + z*q);
  }
}

template<typename ST>
static void run_pipeline(void* const* d_in, float* out, ST* ws, hipStream_t stream){
  const float* ctx = (const float*)d_in[1];
  const float* gh  = (const float*)d_in[2];
  const float *e1w=(const float*)d_in[3],  *e1b=(const float*)d_in[4];
  const float *e2w=(const float*)d_in[5],  *e2b=(const float*)d_in[6];
  const float *e3w=(const float*)d_in[7],  *e3b=(const float*)d_in[8];
  const float *e4w=(const float*)d_in[9],  *e4b=(const float*)d_in[10];
  const float *z1w=(const float*)d_in[11], *z1b=(const float*)d_in[12];
  const float *r1w=(const float*)d_in[13], *r1b=(const float*)d_in[14];
  const float *q1w=(const float*)d_in[15], *q1b=(const float*)d_in[16];
  const float *z2w=(const float*)d_in[17], *z2b=(const float*)d_in[18];
  const float *r2w=(const float*)d_in[19], *r2b=(const float*)d_in[20];
  const float *q2w=(const float*)d_in[21], *q2b=(const float*)d_in[22];
  const float *p1w=(const float*)d_in[23], *p1b=(const float*)d_in[24];
  const float *p2w=(const float*)d_in[25], *p2b=(const float*)d_in[26];

  ST* h    = ws;
  ST* d4   = h    + (size_t)NB*HD*HW;
  ST* bufA = d4   + (size_t)NB*OCH*HW;
  ST* bufB = bufA + (size_t)NB*HD*HW;
  ST* edges= bufB + (size_t)NB*HD*HW;
  ST* cd   = edges+ (size_t)NB*(BN+1)*HW;
  ST* lgts = cd   + (size_t)NB*BN*HW;

  const dim3 blk(256);
  const int PXB = BHW/256;

  k_init<ST><<<dim3((NB*HD*HW+255)/256), blk, 0, stream>>>(gh, h, edges, cd);

  for (int it=0; it<6; ++it){
    k_conv<ST,16,7,7,1> <<<dim3(PXB,32), blk, 0, stream>>>(cd,   e1w, e1b, bufA, HD);
    k_conv<ST,128,3,3,1><<<dim3(PXB,32), blk, 0, stream>>>(bufA, e2w, e2b, bufB, HD);
    k_conv<ST,128,3,3,1><<<dim3(PXB,32), blk, 0, stream>>>(bufB, e3w, e3b, bufA, HD);
    k_conv<ST,128,3,3,1><<<dim3(PXB,64), blk, 0, stream>>>(bufA, e4w, e4b, d4,  OCH);
    k_gru_zr<ST,0><<<dim3(PXB,32), blk, 0, stream>>>(h, d4, ctx, z1w, z1b, r1w, r1b, bufA, bufB);
    k_gru_q <ST,0><<<dim3(PXB,32), blk, 0, stream>>>(bufB, d4, ctx, q1w, q1b, bufA, h);
    k_gru_zr<ST,1><<<dim3(PXB,32), blk, 0, stream>>>(h, d4, ctx, z2w, z2b, r2w, r2b, bufA, bufB);
    k_gru_q <ST,1><<<dim3(PXB,32), blk, 0, stream>>>(bufB, d4, ctx, q2w, q2b, bufA, h);
    k_conv<ST,128,3,3,1><<<dim3(PXB,32), blk, 0, stream>>>(h,    p1w, p1b, bufA, HD);
    k_conv<ST,128,3,3,0><<<dim3(PXB, 4), blk, 0, stream>>>(bufA, p2w, p2b, lgts, 16);
    k_stats<ST><<<dim3(PXB), blk, 0, stream>>>(lgts, edges, cd, out, it);
  }
}

// ============================ fast pipeline ===============================
static void run_fast(void* const* d_in, float* out, double* ws, hipStream_t stream){
  const float* ctx = (const float*)d_in[1];
  const float* gh  = (const float*)d_in[2];
  const float *e1w=(const float*)d_in[3],  *e1b=(const float*)d_in[4];
  const float *e2w=(const float*)d_in[5],  *e2b=(const float*)d_in[6];
  const float *e3w=(const float*)d_in[7],  *e3b=(const float*)d_in[8];
  const float *e4w=(const float*)d_in[9],  *e4b=(const float*)d_in[10];
  const float *z1w=(const float*)d_in[11], *z1b=(const float*)d_in[12];
  const float *r1w=(const float*)d_in[13], *r1b=(const float*)d_in[14];
  const float *q1w=(const float*)d_in[15], *q1b=(const float*)d_in[16];
  const float *z2w=(const float*)d_in[17], *z2b=(const float*)d_in[18];
  const float *r2w=(const float*)d_in[19], *r2b=(const float*)d_in[20];
  const float *q2w=(const float*)d_in[21], *q2b=(const float*)d_in[22];
  const float *p1w=(const float*)d_in[23], *p1b=(const float*)d_in[24];
  const float *p2w=(const float*)d_in[25], *p2b=(const float*)d_in[26];

  double* h    = ws;
  double* d4   = h    + (size_t)NB*HD*HW;
  double* bufA = d4   + (size_t)NB*OCH*HW;
  double* bufB = bufA + (size_t)NB*HD*HW;
  double* edges= bufB + (size_t)NB*HD*HW;
  double* cd   = edges+ (size_t)NB*(BN+1)*HW;
  double* lgts = cd   + (size_t)NB*BN*HW;
  double* wp   = lgts + (size_t)NB*BN*HW;
  double* we1 = wp;             wp += (size_t)HD*16*49;
  double* we2 = wp;             wp += (size_t)HD*HD*9;
  double* we3 = wp;             wp += (size_t)HD*HD*9;
  double* we4 = wp;             wp += (size_t)OCH*HD*9;
  double* wz1 = wp;             wp += (size_t)HD*GC*5;
  double* wr1 = wp;             wp += (size_t)HD*GC*5;
  double* wq1 = wp;             wp += (size_t)HD*GC*5;
  double* wz2 = wp;             wp += (size_t)HD*GC*5;
  double* wr2 = wp;             wp += (size_t)HD*GC*5;
  double* wq2 = wp;             wp += (size_t)HD*GC*5;
  double* wp1 = wp;             wp += (size_t)HD*HD*9;
  double* wp2 = wp;             wp += (size_t)16*HD*9;

  const dim3 blk(256);

  #define XP(src,dst,Cout_,CIN_,TAPS_) { const int n=(Cout_)*(CIN_)*(TAPS_); \
    k_wxpose<<<dim3((n+255)/256), blk, 0, stream>>>(src, dst, Cout_, CIN_, TAPS_, n); }
  XP(e1w, we1, HD, 16, 49); XP(e2w, we2, HD, HD, 9); XP(e3w, we3, HD, HD, 9);
  XP(e4w, we4, OCH, HD, 9);
  XP(z1w, wz1, HD, GC, 5); XP(r1w, wr1, HD, GC, 5); XP(q1w, wq1, HD, GC, 5);
  XP(z2w, wz2, HD, GC, 5); XP(r2w, wr2, HD, GC, 5); XP(q2w, wq2, HD, GC, 5);
  XP(p1w, wp1, HD, HD, 9); XP(p2w, wp2, 16, HD, 9);
  #undef XP

  k_init<double><<<dim3((NB*HD*HW+255)/256), blk, 0, stream>>>(gh, h, edges, cd);

  const int G4 = GXP*4;
  const int G8 = GXP*8;
  const int PXB = BHW/256;

  for (int it=0; it<6; ++it){
    k_fconv<16 ,7,7,8,4,1><<<dim3(G4), blk, 0, stream>>>(cd,   we1, e1b, bufA, HD);
    k_fconv<128,3,3,8,4,1><<<dim3(G4), blk, 0, stream>>>(bufA, we2, e2b, bufB, HD);
    k_fconv<128,3,3,8,4,1><<<dim3(G4), blk, 0, stream>>>(bufB, we3, e3b, bufA, HD);
    k_fconv<128,3,3,8,8,1><<<dim3(G8), blk, 0, stream>>>(bufA, we4, e4b, d4,  OCH);
    // horizontal GRU: fused z+r, then q + h-update
    k_fgru_zr<0><<<dim3(G4), blk, 0, stream>>>(h, d4, ctx, wz1, wr1, z1b, r1b, bufA, bufB);
    k_fgru_q <0><<<dim3(G4), blk, 0, stream>>>(bufB, d4, ctx, wq1, q1b, bufA, h);
    // vertical GRU
    k_fgru_zr<1><<<dim3(G4), blk, 0, stream>>>(h, d4, ctx, wz2, wr2, z2b, r2b, bufA, bufB);
    k_fgru_q <1><<<dim3(G4), blk, 0, stream>>>(bufB, d4, ctx, wq2, q2b, bufA, h);
    // PHead
    k_fconv<128,3,3,8,4,1><<<dim3(G4),  blk, 0, stream>>>(h,    wp1, p1b, bufA, HD);
    k_fconv<128,3,3,4,1,0><<<dim3(PXT), blk, 0, stream>>>(bufA, wp2, p2b, lgts, 16);
    k_stats<double><<<dim3(PXB), blk, 0, stream>>>(lgts, edges, cd, out, it);
  }
}

// ----------------------------------------------------------- launcher ----
extern "C" void kernel_launch(void* const* d_in, const int* in_sizes, int n_in,
                              void* d_out, int out_size, void* d_ws, size_t ws_size,
                              hipStream_t stream){
  const size_t act_d  = (size_t)NB*(HD + OCH + HD + HD + (BN+1) + BN + BN)*HW; // doubles
  const size_t wt_d   = (size_t)HD*16*49 + 3*(size_t)HD*HD*9 + (size_t)OCH*HD*9
                      + 6*(size_t)HD*GC*5 + (size_t)16*HD*9;
  const size_t need_fast = (act_d + wt_d) * sizeof(double);   // ~236 MB
  const size_t need_dbl  = act_d * sizeof(double);            // ~212 MB
  if (ws_size >= need_fast)
    run_fast(d_in, (float*)d_out, (double*)d_ws, stream);
  else if (ws_size >= need_dbl)
    run_pipeline<double>(d_in, (float*)d_out, (double*)d_ws, stream);
  else
    run_pipeline<float >(d_in, (float*)d_out, (float*)d_ws, stream);
}